// Round 1
// baseline (3212.619 us; speedup 1.0000x reference)
//
#include <hip/hip_runtime.h>
#include <math.h>

#define B_SZ   32
#define C_DIM  384
#define H_IN   28
#define W_IN   28
#define TQ     785   // 1 + 28*28
#define TKV    197   // 1 + 14*14
#define NH     6
#define HD     64
#define SCALE_F 0.05103103630798287f  // 384^-0.5
#define BN_EPS_F 1e-5f

// ---------------- depthwise 3x3 conv + BN ----------------
// x: (B, TQ, C) fp32 tokens; writes out rows [1 .. HO*WO] of out (B, 1+HO*WO, C)
__global__ __launch_bounds__(256) void dwconv_bn_kernel(
    const float* __restrict__ x,
    const float* __restrict__ cw,     // (C,1,3,3) slice
    const float* __restrict__ gamma,
    const float* __restrict__ beta,
    const float* __restrict__ mean,
    const float* __restrict__ var,
    float* __restrict__ out,
    int stride, int HO, int WO)
{
    int idx = blockIdx.x * 256 + threadIdx.x;
    int total = B_SZ * HO * WO * C_DIM;
    if (idx >= total) return;
    int c = idx % C_DIM;
    int p = (idx / C_DIM) % (HO * WO);
    int b = idx / (C_DIM * HO * WO);
    int oi = p / WO, oj = p % WO;

    float acc = 0.f;
#pragma unroll
    for (int di = 0; di < 3; ++di) {
        int ii = oi * stride + di - 1;
        if (ii < 0 || ii >= H_IN) continue;
#pragma unroll
        for (int dj = 0; dj < 3; ++dj) {
            int jj = oj * stride + dj - 1;
            if (jj < 0 || jj >= W_IN) continue;
            float xv = x[((size_t)b * TQ + 1 + ii * W_IN + jj) * C_DIM + c];
            acc += cw[c * 9 + di * 3 + dj] * xv;
        }
    }
    float inv = gamma[c] * rsqrtf(var[c] + BN_EPS_F);
    float y = acc * inv + (beta[c] - mean[c] * inv);
    out[((size_t)b * (1 + HO * WO) + 1 + p) * C_DIM + c] = y;
}

// copy cls token (x[b,0,:]) into row 0 of each token buffer
__global__ __launch_bounds__(256) void cls_copy_kernel(
    const float* __restrict__ x,
    float* __restrict__ q_tok, float* __restrict__ k_tok, float* __restrict__ v_tok)
{
    int idx = blockIdx.x * 256 + threadIdx.x;
    if (idx >= B_SZ * C_DIM) return;
    int c = idx % C_DIM, b = idx / C_DIM;
    float v = x[(size_t)b * TQ * C_DIM + c];
    q_tok[(size_t)b * TQ * C_DIM + c] = v;
    k_tok[(size_t)b * TKV * C_DIM + c] = v;
    v_tok[(size_t)b * TKV * C_DIM + c] = v;
}

// ---------------- fp32 GEMM: C[m][n] = sum_k A[m][k] * W[n][k] (+bias) ----------------
// K = N = 384. grid: (N/64, ceil(M/64)); block 256 (16x16 threads, 4x4 acc each)
__global__ __launch_bounds__(256) void gemm_nt_kernel(
    const float* __restrict__ A,
    const float* __restrict__ W,
    const float* __restrict__ bias,
    float* __restrict__ Cmat,
    int M)
{
    __shared__ float As[16][65];
    __shared__ float Ws[16][65];
    int bm = blockIdx.y * 64;
    int bn = blockIdx.x * 64;
    int tid = threadIdx.x;
    int tx = tid & 15, ty = tid >> 4;

    float acc[4][4] = {};

    for (int k0 = 0; k0 < 384; k0 += 16) {
        int k = tid & 15;
        int m0 = tid >> 4;
#pragma unroll
        for (int r = 0; r < 4; ++r) {
            int m = m0 + r * 16;
            int gm = bm + m;
            As[k][m] = (gm < M) ? A[(size_t)gm * 384 + k0 + k] : 0.f;
            Ws[k][m] = W[(size_t)(bn + m) * 384 + k0 + k];
        }
        __syncthreads();
#pragma unroll
        for (int kk = 0; kk < 16; ++kk) {
            float a[4], w[4];
#pragma unroll
            for (int i = 0; i < 4; ++i) a[i] = As[kk][ty * 4 + i];
#pragma unroll
            for (int j = 0; j < 4; ++j) w[j] = Ws[kk][tx * 4 + j];
#pragma unroll
            for (int i = 0; i < 4; ++i)
#pragma unroll
                for (int j = 0; j < 4; ++j)
                    acc[i][j] += a[i] * w[j];
        }
        __syncthreads();
    }

    float bj[4] = {0.f, 0.f, 0.f, 0.f};
    if (bias) {
#pragma unroll
        for (int j = 0; j < 4; ++j) bj[j] = bias[bn + tx * 4 + j];
    }
#pragma unroll
    for (int i = 0; i < 4; ++i) {
        int gm = bm + ty * 4 + i;
        if (gm >= M) continue;
        float4 o;
        o.x = acc[i][0] + bj[0];
        o.y = acc[i][1] + bj[1];
        o.z = acc[i][2] + bj[2];
        o.w = acc[i][3] + bj[3];
        *(float4*)&Cmat[(size_t)gm * 384 + bn + tx * 4] = o;
    }
}

// ---------------- attention: per-wave softmax over 197 keys ----------------
// Q: (B, TQ, 384) head-interleaved; K,V: (B, TKV, 384); O: (B, TQ, 384)
// grid: (ceil(TQ/32), NH, B); block 256 = 4 waves; each wave does 8 queries
__global__ __launch_bounds__(256) void attn_kernel(
    const float* __restrict__ Q,
    const float* __restrict__ K,
    const float* __restrict__ V,
    float* __restrict__ O)
{
    __shared__ float sm[4][224];  // per-wave logit buffer (197 used)
    int w = threadIdx.x >> 6, lane = threadIdx.x & 63;
    int h = blockIdx.y, b = blockIdx.z;
    const float* Qb = Q + (size_t)b * TQ * C_DIM + h * HD;
    const float* Kb = K + (size_t)b * TKV * C_DIM + h * HD;
    const float* Vb = V + (size_t)b * TKV * C_DIM + h * HD;
    float* Ob = O + (size_t)b * TQ * C_DIM + h * HD;

    for (int qi = 0; qi < 8; ++qi) {
        int t = blockIdx.x * 32 + qi * 4 + w;
        if (t >= TQ) break;  // wave-uniform

        float qd = Qb[(size_t)t * C_DIM + lane] * SCALE_F;

        // pass 1: logits + max
        float mx = -1e30f;
        for (int tk = 0; tk < TKV; ++tk) {
            float p = qd * Kb[(size_t)tk * C_DIM + lane];
            p += __shfl_xor(p, 32);
            p += __shfl_xor(p, 16);
            p += __shfl_xor(p, 8);
            p += __shfl_xor(p, 4);
            p += __shfl_xor(p, 2);
            p += __shfl_xor(p, 1);
            if (lane == 0) sm[w][tk] = p;
            mx = fmaxf(mx, p);
        }

        // pass 2: exp + denom (wave-internal; no barrier needed)
        float sum = 0.f;
        for (int tk = lane; tk < TKV; tk += 64) {
            float e = __expf(sm[w][tk] - mx);
            sm[w][tk] = e;
            sum += e;
        }
        sum += __shfl_xor(sum, 32);
        sum += __shfl_xor(sum, 16);
        sum += __shfl_xor(sum, 8);
        sum += __shfl_xor(sum, 4);
        sum += __shfl_xor(sum, 2);
        sum += __shfl_xor(sum, 1);
        float inv = 1.f / sum;

        // pass 3: weighted sum of V (lane = head dim)
        float o = 0.f;
        for (int tk = 0; tk < TKV; ++tk)
            o += sm[w][tk] * Vb[(size_t)tk * C_DIM + lane];

        Ob[(size_t)t * C_DIM + lane] = o * inv;
    }
}

extern "C" void kernel_launch(void* const* d_in, const int* in_sizes, int n_in,
                              void* d_out, int out_size, void* d_ws, size_t ws_size,
                              hipStream_t stream) {
    const float* x       = (const float*)d_in[0];
    const float* conv_w  = (const float*)d_in[1];   // (3, C, 1, 3, 3)
    const float* bn_g    = (const float*)d_in[2];   // (3, C)
    const float* bn_b    = (const float*)d_in[3];
    const float* bn_m    = (const float*)d_in[4];
    const float* bn_v    = (const float*)d_in[5];
    const float* w_q     = (const float*)d_in[6];   // (C, C)
    const float* w_k     = (const float*)d_in[7];
    const float* w_v     = (const float*)d_in[8];
    const float* w_proj  = (const float*)d_in[9];
    const float* b_proj  = (const float*)d_in[10];
    float* out = (float*)d_out;

    const size_t NQ = (size_t)B_SZ * TQ * C_DIM;    // 9,646,080
    const size_t NKV = (size_t)B_SZ * TKV * C_DIM;  // 2,420,736

    float* ws = (float*)d_ws;
    float* q_tok = ws;
    float* k_tok = q_tok + NQ;
    float* v_tok = k_tok + NKV;
    float* Qp    = v_tok + NKV;
    float* Kp    = Qp + NQ;
    float* Vp    = Kp + NKV;
    float* attn_out = q_tok;   // q_tok dead after Q projection

    // 1) depthwise conv + BN
    {
        int total_q = B_SZ * 28 * 28 * C_DIM;
        dwconv_bn_kernel<<<(total_q + 255) / 256, 256, 0, stream>>>(
            x, conv_w + 0 * C_DIM * 9, bn_g + 0 * C_DIM, bn_b + 0 * C_DIM,
            bn_m + 0 * C_DIM, bn_v + 0 * C_DIM, q_tok, 1, 28, 28);
        int total_kv = B_SZ * 14 * 14 * C_DIM;
        dwconv_bn_kernel<<<(total_kv + 255) / 256, 256, 0, stream>>>(
            x, conv_w + 1 * C_DIM * 9, bn_g + 1 * C_DIM, bn_b + 1 * C_DIM,
            bn_m + 1 * C_DIM, bn_v + 1 * C_DIM, k_tok, 2, 14, 14);
        dwconv_bn_kernel<<<(total_kv + 255) / 256, 256, 0, stream>>>(
            x, conv_w + 2 * C_DIM * 9, bn_g + 2 * C_DIM, bn_b + 2 * C_DIM,
            bn_m + 2 * C_DIM, bn_v + 2 * C_DIM, v_tok, 2, 14, 14);
        cls_copy_kernel<<<(B_SZ * C_DIM + 255) / 256, 256, 0, stream>>>(
            x, q_tok, k_tok, v_tok);
    }

    // 2) Q/K/V projections
    {
        int Mq = B_SZ * TQ;   // 25120
        int Mkv = B_SZ * TKV; // 6304
        dim3 gq(6, (Mq + 63) / 64);
        dim3 gkv(6, (Mkv + 63) / 64);
        gemm_nt_kernel<<<gq, 256, 0, stream>>>(q_tok, w_q, nullptr, Qp, Mq);
        gemm_nt_kernel<<<gkv, 256, 0, stream>>>(k_tok, w_k, nullptr, Kp, Mkv);
        gemm_nt_kernel<<<gkv, 256, 0, stream>>>(v_tok, w_v, nullptr, Vp, Mkv);
    }

    // 3) attention
    {
        dim3 ga((TQ + 31) / 32, NH, B_SZ);
        attn_kernel<<<ga, 256, 0, stream>>>(Qp, Kp, Vp, attn_out);
    }

    // 4) output projection + bias
    {
        int Mq = B_SZ * TQ;
        dim3 gp(6, (Mq + 63) / 64);
        gemm_nt_kernel<<<gp, 256, 0, stream>>>(attn_out, w_proj, b_proj, out, Mq);
    }
}

// Round 2
// 764.445 us; speedup vs baseline: 4.2025x; 4.2025x over previous
//
#include <hip/hip_runtime.h>
#include <math.h>

#define B_SZ   32
#define C_DIM  384
#define H_IN   28
#define W_IN   28
#define TQ     785   // 1 + 28*28
#define TKV    197   // 1 + 14*14
#define NH     6
#define HD     64
#define SCALE_F 0.05103103630798287f  // 384^-0.5
#define BN_EPS_F 1e-5f

#define FMA4(acc, s, v) { (acc).x += (s)*(v).x; (acc).y += (s)*(v).y; (acc).z += (s)*(v).z; (acc).w += (s)*(v).w; }

// ---------------- depthwise 3x3 conv + BN ----------------
__global__ __launch_bounds__(256) void dwconv_bn_kernel(
    const float* __restrict__ x,
    const float* __restrict__ cw,
    const float* __restrict__ gamma,
    const float* __restrict__ beta,
    const float* __restrict__ mean,
    const float* __restrict__ var,
    float* __restrict__ out,
    int stride, int HO, int WO)
{
    int idx = blockIdx.x * 256 + threadIdx.x;
    int total = B_SZ * HO * WO * C_DIM;
    if (idx >= total) return;
    int c = idx % C_DIM;
    int p = (idx / C_DIM) % (HO * WO);
    int b = idx / (C_DIM * HO * WO);
    int oi = p / WO, oj = p % WO;

    float acc = 0.f;
#pragma unroll
    for (int di = 0; di < 3; ++di) {
        int ii = oi * stride + di - 1;
        if (ii < 0 || ii >= H_IN) continue;
#pragma unroll
        for (int dj = 0; dj < 3; ++dj) {
            int jj = oj * stride + dj - 1;
            if (jj < 0 || jj >= W_IN) continue;
            float xv = x[((size_t)b * TQ + 1 + ii * W_IN + jj) * C_DIM + c];
            acc += cw[c * 9 + di * 3 + dj] * xv;
        }
    }
    float inv = gamma[c] * rsqrtf(var[c] + BN_EPS_F);
    float y = acc * inv + (beta[c] - mean[c] * inv);
    out[((size_t)b * (1 + HO * WO) + 1 + p) * C_DIM + c] = y;
}

__global__ __launch_bounds__(256) void cls_copy_kernel(
    const float* __restrict__ x,
    float* __restrict__ q_tok, float* __restrict__ k_tok, float* __restrict__ v_tok)
{
    int idx = blockIdx.x * 256 + threadIdx.x;
    if (idx >= B_SZ * C_DIM) return;
    int c = idx % C_DIM, b = idx / C_DIM;
    float v = x[(size_t)b * TQ * C_DIM + c];
    q_tok[(size_t)b * TQ * C_DIM + c] = v;
    k_tok[(size_t)b * TKV * C_DIM + c] = v;
    v_tok[(size_t)b * TKV * C_DIM + c] = v;
}

// ---------------- fp32 GEMM: C[m][n] = sum_k A[m][k] * W[n][k] (+bias) ----------------
// K = N = 384. grid: (6, ceil(M/64)); block 256 (16x16 threads, 4x4 acc each)
__global__ __launch_bounds__(256) void gemm_nt_kernel(
    const float* __restrict__ A,
    const float* __restrict__ W,
    const float* __restrict__ bias,
    float* __restrict__ Cmat,
    int M)
{
    __shared__ float As[16][68];   // 68: keeps rows 16B-aligned for float4 reads
    __shared__ float Ws[16][68];
    int bm = blockIdx.y * 64;
    int bn = blockIdx.x * 64;
    int tid = threadIdx.x;
    int tx = tid & 15, ty = tid >> 4;

    float4 acc[4];
    acc[0] = make_float4(0.f, 0.f, 0.f, 0.f);
    acc[1] = acc[0]; acc[2] = acc[0]; acc[3] = acc[0];

    for (int k0 = 0; k0 < 384; k0 += 16) {
        int k = tid & 15;
        int m0 = tid >> 4;
#pragma unroll
        for (int r = 0; r < 4; ++r) {
            int m = m0 + r * 16;
            int gm = bm + m;
            As[k][m] = (gm < M) ? A[(size_t)gm * 384 + k0 + k] : 0.f;
            Ws[k][m] = W[(size_t)(bn + m) * 384 + k0 + k];
        }
        __syncthreads();
#pragma unroll
        for (int kk = 0; kk < 16; ++kk) {
            float4 a4 = *(const float4*)&As[kk][ty * 4];
            float4 w4 = *(const float4*)&Ws[kk][tx * 4];
            FMA4(acc[0], a4.x, w4);
            FMA4(acc[1], a4.y, w4);
            FMA4(acc[2], a4.z, w4);
            FMA4(acc[3], a4.w, w4);
        }
        __syncthreads();
    }

    float4 bj = make_float4(0.f, 0.f, 0.f, 0.f);
    if (bias) bj = *(const float4*)&bias[bn + tx * 4];
#pragma unroll
    for (int i = 0; i < 4; ++i) {
        int gm = bm + ty * 4 + i;
        if (gm >= M) continue;
        float4 o;
        o.x = acc[i].x + bj.x;
        o.y = acc[i].y + bj.y;
        o.z = acc[i].z + bj.z;
        o.w = acc[i].w + bj.w;
        *(float4*)&Cmat[(size_t)gm * 384 + bn + tx * 4] = o;
    }
}

// ---------------- fused tile attention ----------------
// Per block: 32 queries x one (b,h). S = Q K^T (reg-tiled LDS GEMM),
// row softmax, O = P V (reg-tiled LDS GEMM). No per-element shuffles.
#define TILE_Q 32
#define SS_W   200
#define KPAD   68

__global__ __launch_bounds__(256) void attn_v2(
    const float* __restrict__ Q,
    const float* __restrict__ K,
    const float* __restrict__ V,
    float* __restrict__ O)
{
    __shared__ float Qs[TILE_Q][KPAD];
    __shared__ float KVs[64][KPAD];   // K^T per tile (dim-major), then V (key-major)
    __shared__ float Ss[TILE_Q][SS_W];
    __shared__ float invs[TILE_Q];

    int t = threadIdx.x;
    int h = blockIdx.y, b = blockIdx.z;
    int q0 = blockIdx.x * TILE_Q;
    const float* Qb = Q + (size_t)b * TQ * C_DIM + h * HD;
    const float* Kb = K + (size_t)b * TKV * C_DIM + h * HD;
    const float* Vb = V + (size_t)b * TKV * C_DIM + h * HD;
    float* Ob = O + (size_t)b * TQ * C_DIM + h * HD;

    // load Q tile (zero-fill invalid rows)
#pragma unroll
    for (int r = 0; r < 2; ++r) {
        int idx = t + 256 * r;           // 512 float4
        int row = idx >> 4, seg = idx & 15;
        float4 v = make_float4(0.f, 0.f, 0.f, 0.f);
        int gq = q0 + row;
        if (gq < TQ) v = *(const float4*)&Qb[(size_t)gq * C_DIM + seg * 4];
        *(float4*)&Qs[row][seg * 4] = v;
    }

    int tx = t & 15, ty = t >> 4;
    int qa = ty * 2, qb = qa + 1;

    // ---- S = Q K^T, key tiles of 64 ----
    for (int kt = 0; kt < 4; ++kt) {
        int k0 = kt * 64;
        if (kt > 0) __syncthreads();     // prior GEMM done reading KVs
        // load K tile transposed: KVs[dim][key]
#pragma unroll
        for (int r = 0; r < 4; ++r) {
            int idx = t + 256 * r;       // 1024 float4
            int key = idx >> 4, seg = idx & 15;
            float4 v = make_float4(0.f, 0.f, 0.f, 0.f);
            int gk = k0 + key;
            if (gk < TKV) v = *(const float4*)&Kb[(size_t)gk * C_DIM + seg * 4];
            KVs[seg * 4 + 0][key] = v.x;
            KVs[seg * 4 + 1][key] = v.y;
            KVs[seg * 4 + 2][key] = v.z;
            KVs[seg * 4 + 3][key] = v.w;
        }
        __syncthreads();

        float4 acc_a = make_float4(0.f, 0.f, 0.f, 0.f);
        float4 acc_b = acc_a;
#pragma unroll
        for (int i = 0; i < 16; ++i) {
            float4 A0 = *(const float4*)&Qs[qa][i * 4];
            float4 A1 = *(const float4*)&Qs[qb][i * 4];
            float4 B0 = *(const float4*)&KVs[i * 4 + 0][tx * 4];
            float4 B1 = *(const float4*)&KVs[i * 4 + 1][tx * 4];
            float4 B2 = *(const float4*)&KVs[i * 4 + 2][tx * 4];
            float4 B3 = *(const float4*)&KVs[i * 4 + 3][tx * 4];
            FMA4(acc_a, A0.x, B0); FMA4(acc_a, A0.y, B1);
            FMA4(acc_a, A0.z, B2); FMA4(acc_a, A0.w, B3);
            FMA4(acc_b, A1.x, B0); FMA4(acc_b, A1.y, B1);
            FMA4(acc_b, A1.z, B2); FMA4(acc_b, A1.w, B3);
        }
        if (kt < 3) {
            float4 sa = make_float4(acc_a.x * SCALE_F, acc_a.y * SCALE_F,
                                    acc_a.z * SCALE_F, acc_a.w * SCALE_F);
            float4 sb = make_float4(acc_b.x * SCALE_F, acc_b.y * SCALE_F,
                                    acc_b.z * SCALE_F, acc_b.w * SCALE_F);
            *(float4*)&Ss[qa][k0 + tx * 4] = sa;
            *(float4*)&Ss[qb][k0 + tx * 4] = sb;
        } else {
            float av[4] = {acc_a.x, acc_a.y, acc_a.z, acc_a.w};
            float bv[4] = {acc_b.x, acc_b.y, acc_b.z, acc_b.w};
#pragma unroll
            for (int c = 0; c < 4; ++c) {
                int key = k0 + tx * 4 + c;
                if (key < TKV) {
                    Ss[qa][key] = av[c] * SCALE_F;
                    Ss[qb][key] = bv[c] * SCALE_F;
                }
            }
        }
    }
    __syncthreads();

    // ---- row softmax: 8 lanes per row ----
    {
        int row = t >> 3, j = t & 7;
        float mx = -1e30f;
        for (int tk = j; tk < TKV; tk += 8) mx = fmaxf(mx, Ss[row][tk]);
        mx = fmaxf(mx, __shfl_xor(mx, 1));
        mx = fmaxf(mx, __shfl_xor(mx, 2));
        mx = fmaxf(mx, __shfl_xor(mx, 4));
        float sum = 0.f;
        for (int tk = j; tk < TKV; tk += 8) {
            float e = __expf(Ss[row][tk] - mx);
            Ss[row][tk] = e;
            sum += e;
        }
        sum += __shfl_xor(sum, 1);
        sum += __shfl_xor(sum, 2);
        sum += __shfl_xor(sum, 4);
        if (j == 0) invs[row] = 1.f / sum;
    }
    __syncthreads();

    // ---- O = P V, key tiles of 64 (3 full tiles + 5-key tail) ----
    float4 oacc_a = make_float4(0.f, 0.f, 0.f, 0.f);
    float4 oacc_b = oacc_a;
    for (int vt = 0; vt < 3; ++vt) {
        if (vt > 0) __syncthreads();
#pragma unroll
        for (int r = 0; r < 4; ++r) {
            int idx = t + 256 * r;
            int row = idx >> 4, seg = idx & 15;
            int gk = vt * 64 + row;      // < 192, always valid
            *(float4*)&KVs[row][seg * 4] =
                *(const float4*)&Vb[(size_t)gk * C_DIM + seg * 4];
        }
        __syncthreads();
#pragma unroll
        for (int i = 0; i < 16; ++i) {
            float4 pa = *(const float4*)&Ss[qa][vt * 64 + i * 4];
            float4 pb = *(const float4*)&Ss[qb][vt * 64 + i * 4];
            float4 V0 = *(const float4*)&KVs[i * 4 + 0][tx * 4];
            float4 V1 = *(const float4*)&KVs[i * 4 + 1][tx * 4];
            float4 V2 = *(const float4*)&KVs[i * 4 + 2][tx * 4];
            float4 V3 = *(const float4*)&KVs[i * 4 + 3][tx * 4];
            FMA4(oacc_a, pa.x, V0); FMA4(oacc_a, pa.y, V1);
            FMA4(oacc_a, pa.z, V2); FMA4(oacc_a, pa.w, V3);
            FMA4(oacc_b, pb.x, V0); FMA4(oacc_b, pb.y, V1);
            FMA4(oacc_b, pb.z, V2); FMA4(oacc_b, pb.w, V3);
        }
    }
    __syncthreads();
    if (t < 80) {                        // 5 tail rows (keys 192..196)
        int row = t >> 4, seg = t & 15;
        *(float4*)&KVs[row][seg * 4] =
            *(const float4*)&Vb[(size_t)(192 + row) * C_DIM + seg * 4];
    }
    __syncthreads();
#pragma unroll
    for (int i = 0; i < 5; ++i) {
        float pa = Ss[qa][192 + i];
        float pb = Ss[qb][192 + i];
        float4 v4 = *(const float4*)&KVs[i][tx * 4];
        FMA4(oacc_a, pa, v4);
        FMA4(oacc_b, pb, v4);
    }

    float ia = invs[qa], ib = invs[qb];
    int gqa = q0 + qa, gqb = q0 + qb;
    if (gqa < TQ) {
        float4 o = make_float4(oacc_a.x * ia, oacc_a.y * ia, oacc_a.z * ia, oacc_a.w * ia);
        *(float4*)&Ob[(size_t)gqa * C_DIM + tx * 4] = o;
    }
    if (gqb < TQ) {
        float4 o = make_float4(oacc_b.x * ib, oacc_b.y * ib, oacc_b.z * ib, oacc_b.w * ib);
        *(float4*)&Ob[(size_t)gqb * C_DIM + tx * 4] = o;
    }
}

extern "C" void kernel_launch(void* const* d_in, const int* in_sizes, int n_in,
                              void* d_out, int out_size, void* d_ws, size_t ws_size,
                              hipStream_t stream) {
    const float* x       = (const float*)d_in[0];
    const float* conv_w  = (const float*)d_in[1];
    const float* bn_g    = (const float*)d_in[2];
    const float* bn_b    = (const float*)d_in[3];
    const float* bn_m    = (const float*)d_in[4];
    const float* bn_v    = (const float*)d_in[5];
    const float* w_q     = (const float*)d_in[6];
    const float* w_k     = (const float*)d_in[7];
    const float* w_v     = (const float*)d_in[8];
    const float* w_proj  = (const float*)d_in[9];
    const float* b_proj  = (const float*)d_in[10];
    float* out = (float*)d_out;

    const size_t NQ = (size_t)B_SZ * TQ * C_DIM;
    const size_t NKV = (size_t)B_SZ * TKV * C_DIM;

    float* ws = (float*)d_ws;
    float* q_tok = ws;
    float* k_tok = q_tok + NQ;
    float* v_tok = k_tok + NKV;
    float* Qp    = v_tok + NKV;
    float* Kp    = Qp + NQ;
    float* Vp    = Kp + NKV;
    float* attn_out = q_tok;   // q_tok dead after Q projection

    // 1) depthwise conv + BN
    {
        int total_q = B_SZ * 28 * 28 * C_DIM;
        dwconv_bn_kernel<<<(total_q + 255) / 256, 256, 0, stream>>>(
            x, conv_w + 0 * C_DIM * 9, bn_g + 0 * C_DIM, bn_b + 0 * C_DIM,
            bn_m + 0 * C_DIM, bn_v + 0 * C_DIM, q_tok, 1, 28, 28);
        int total_kv = B_SZ * 14 * 14 * C_DIM;
        dwconv_bn_kernel<<<(total_kv + 255) / 256, 256, 0, stream>>>(
            x, conv_w + 1 * C_DIM * 9, bn_g + 1 * C_DIM, bn_b + 1 * C_DIM,
            bn_m + 1 * C_DIM, bn_v + 1 * C_DIM, k_tok, 2, 14, 14);
        dwconv_bn_kernel<<<(total_kv + 255) / 256, 256, 0, stream>>>(
            x, conv_w + 2 * C_DIM * 9, bn_g + 2 * C_DIM, bn_b + 2 * C_DIM,
            bn_m + 2 * C_DIM, bn_v + 2 * C_DIM, v_tok, 2, 14, 14);
        cls_copy_kernel<<<(B_SZ * C_DIM + 255) / 256, 256, 0, stream>>>(
            x, q_tok, k_tok, v_tok);
    }

    // 2) Q/K/V projections
    {
        int Mq = B_SZ * TQ;
        int Mkv = B_SZ * TKV;
        dim3 gq(6, (Mq + 63) / 64);
        dim3 gkv(6, (Mkv + 63) / 64);
        gemm_nt_kernel<<<gq, 256, 0, stream>>>(q_tok, w_q, nullptr, Qp, Mq);
        gemm_nt_kernel<<<gkv, 256, 0, stream>>>(k_tok, w_k, nullptr, Kp, Mkv);
        gemm_nt_kernel<<<gkv, 256, 0, stream>>>(v_tok, w_v, nullptr, Vp, Mkv);
    }

    // 3) fused attention
    {
        dim3 ga((TQ + TILE_Q - 1) / TILE_Q, NH, B_SZ);
        attn_v2<<<ga, 256, 0, stream>>>(Qp, Kp, Vp, attn_out);
    }

    // 4) output projection + bias
    {
        int Mq = B_SZ * TQ;
        dim3 gp(6, (Mq + 63) / 64);
        gemm_nt_kernel<<<gp, 256, 0, stream>>>(attn_out, w_proj, b_proj, out, Mq);
    }
}

// Round 3
// 704.015 us; speedup vs baseline: 4.5633x; 1.0858x over previous
//
#include <hip/hip_runtime.h>
#include <math.h>

#define B_SZ   32
#define C_DIM  384
#define H_IN   28
#define W_IN   28
#define TQ     785   // 1 + 28*28
#define TKV    197   // 1 + 14*14
#define NH     6
#define HD     64
#define SCALE_F 0.05103103630798287f  // 384^-0.5
#define BN_EPS_F 1e-5f

#define FMA4(acc, s, v) { (acc).x += (s)*(v).x; (acc).y += (s)*(v).y; (acc).z += (s)*(v).z; (acc).w += (s)*(v).w; }

// ---------------- depthwise 3x3 conv + BN ----------------
__global__ __launch_bounds__(256) void dwconv_bn_kernel(
    const float* __restrict__ x,
    const float* __restrict__ cw,
    const float* __restrict__ gamma,
    const float* __restrict__ beta,
    const float* __restrict__ mean,
    const float* __restrict__ var,
    float* __restrict__ out,
    int stride, int HO, int WO)
{
    int idx = blockIdx.x * 256 + threadIdx.x;
    int total = B_SZ * HO * WO * C_DIM;
    if (idx >= total) return;
    int c = idx % C_DIM;
    int p = (idx / C_DIM) % (HO * WO);
    int b = idx / (C_DIM * HO * WO);
    int oi = p / WO, oj = p % WO;

    float acc = 0.f;
#pragma unroll
    for (int di = 0; di < 3; ++di) {
        int ii = oi * stride + di - 1;
        if (ii < 0 || ii >= H_IN) continue;
#pragma unroll
        for (int dj = 0; dj < 3; ++dj) {
            int jj = oj * stride + dj - 1;
            if (jj < 0 || jj >= W_IN) continue;
            float xv = x[((size_t)b * TQ + 1 + ii * W_IN + jj) * C_DIM + c];
            acc += cw[c * 9 + di * 3 + dj] * xv;
        }
    }
    float inv = gamma[c] * rsqrtf(var[c] + BN_EPS_F);
    float y = acc * inv + (beta[c] - mean[c] * inv);
    out[((size_t)b * (1 + HO * WO) + 1 + p) * C_DIM + c] = y;
}

__global__ __launch_bounds__(256) void cls_copy_kernel(
    const float* __restrict__ x,
    float* __restrict__ q_tok, float* __restrict__ k_tok, float* __restrict__ v_tok)
{
    int idx = blockIdx.x * 256 + threadIdx.x;
    if (idx >= B_SZ * C_DIM) return;
    int c = idx % C_DIM, b = idx / C_DIM;
    float v = x[(size_t)b * TQ * C_DIM + c];
    q_tok[(size_t)b * TQ * C_DIM + c] = v;
    k_tok[(size_t)b * TKV * C_DIM + c] = v;
    v_tok[(size_t)b * TKV * C_DIM + c] = v;
}

// ---------------- fp32 GEMM: C[m][n] = sum_k A[m][k] * W[n][k] (+bias) ----------------
// K = N = 384. grid: (6, ceil(M/64)); block 256 (16x16 threads, 4x4 acc each)
__global__ __launch_bounds__(256) void gemm_nt_kernel(
    const float* __restrict__ A,
    const float* __restrict__ W,
    const float* __restrict__ bias,
    float* __restrict__ Cmat,
    int M)
{
    __shared__ float As[16][68];
    __shared__ float Ws[16][68];
    int bm = blockIdx.y * 64;
    int bn = blockIdx.x * 64;
    int tid = threadIdx.x;
    int tx = tid & 15, ty = tid >> 4;
    int tm = tid >> 2;            // 0..63 staging row
    int ts = (tid & 3) * 4;       // staging k-seg

    float4 acc[4];
    acc[0] = make_float4(0.f, 0.f, 0.f, 0.f);
    acc[1] = acc[0]; acc[2] = acc[0]; acc[3] = acc[0];

    for (int k0 = 0; k0 < 384; k0 += 16) {
        float4 a4 = make_float4(0.f, 0.f, 0.f, 0.f);
        int gm = bm + tm;
        if (gm < M) a4 = *(const float4*)&A[(size_t)gm * 384 + k0 + ts];
        float4 w4 = *(const float4*)&W[(size_t)(bn + tm) * 384 + k0 + ts];
        As[ts + 0][tm] = a4.x; As[ts + 1][tm] = a4.y;
        As[ts + 2][tm] = a4.z; As[ts + 3][tm] = a4.w;
        Ws[ts + 0][tm] = w4.x; Ws[ts + 1][tm] = w4.y;
        Ws[ts + 2][tm] = w4.z; Ws[ts + 3][tm] = w4.w;
        __syncthreads();
#pragma unroll
        for (int kk = 0; kk < 16; ++kk) {
            float4 av = *(const float4*)&As[kk][ty * 4];
            float4 wv = *(const float4*)&Ws[kk][tx * 4];
            FMA4(acc[0], av.x, wv);
            FMA4(acc[1], av.y, wv);
            FMA4(acc[2], av.z, wv);
            FMA4(acc[3], av.w, wv);
        }
        __syncthreads();
    }

    float4 bj = make_float4(0.f, 0.f, 0.f, 0.f);
    if (bias) bj = *(const float4*)&bias[bn + tx * 4];
#pragma unroll
    for (int i = 0; i < 4; ++i) {
        int gm = bm + ty * 4 + i;
        if (gm >= M) continue;
        float4 o;
        o.x = acc[i].x + bj.x;
        o.y = acc[i].y + bj.y;
        o.z = acc[i].z + bj.z;
        o.w = acc[i].w + bj.w;
        *(float4*)&Cmat[(size_t)gm * 384 + bn + tx * 4] = o;
    }
}

// ---------------- flash-style fused attention ----------------
// TILE_Q=64, 256 threads (16 key-lanes x 16 q-groups), 4q x 4k per thread.
// Online softmax: m,l per row in registers; P round-trips via LDS per tile.
#define TILE_Q 64
#define KPAD   68

__global__ __launch_bounds__(256) void attn_v3(
    const float* __restrict__ Q,
    const float* __restrict__ K,
    const float* __restrict__ V,
    float* __restrict__ O)
{
    __shared__ float Qs[TILE_Q][KPAD];   // Q tile [q][dim]
    __shared__ float Ks[64][KPAD];       // K^T [dim][key] then V [key][dim]
    __shared__ float Ps[TILE_Q][KPAD];   // P tile [q][key]

    int t = threadIdx.x;
    int h = blockIdx.y, b = blockIdx.z;
    int q0 = blockIdx.x * TILE_Q;
    const float* Qb = Q + (size_t)b * TQ * C_DIM + h * HD;
    const float* Kb = K + (size_t)b * TKV * C_DIM + h * HD;
    const float* Vb = V + (size_t)b * TKV * C_DIM + h * HD;
    float* Ob = O + (size_t)b * TQ * C_DIM + h * HD;

    int tx = t & 15, ty = t >> 4;
    int qa = ty * 4;                     // rows qa..qa+3

    // stage Q tile (zero-fill rows past TQ)
#pragma unroll
    for (int r = 0; r < 4; ++r) {
        int idx = t + 256 * r;           // 1024 float4
        int row = idx >> 4, seg = idx & 15;
        float4 v = make_float4(0.f, 0.f, 0.f, 0.f);
        int gq = q0 + row;
        if (gq < TQ) v = *(const float4*)&Qb[(size_t)gq * C_DIM + seg * 4];
        *(float4*)&Qs[row][seg * 4] = v;
    }

    float m[4] = {-1e30f, -1e30f, -1e30f, -1e30f};
    float l[4] = {0.f, 0.f, 0.f, 0.f};
    float4 oacc[4];
    oacc[0] = make_float4(0.f, 0.f, 0.f, 0.f);
    oacc[1] = oacc[0]; oacc[2] = oacc[0]; oacc[3] = oacc[0];

    for (int kt = 0; kt < 4; ++kt) {
        int k0 = kt * 64;
        __syncthreads();                 // prev PV done (and Qs staged, 1st iter)

        // stage K^T tile: Ks[dim][key], zeros for keys past TKV
#pragma unroll
        for (int r = 0; r < 4; ++r) {
            int idx = t + 256 * r;
            int key = idx >> 4, seg = idx & 15;
            float4 v = make_float4(0.f, 0.f, 0.f, 0.f);
            int gk = k0 + key;
            if (gk < TKV) v = *(const float4*)&Kb[(size_t)gk * C_DIM + seg * 4];
            Ks[seg * 4 + 0][key] = v.x;
            Ks[seg * 4 + 1][key] = v.y;
            Ks[seg * 4 + 2][key] = v.z;
            Ks[seg * 4 + 3][key] = v.w;
        }
        __syncthreads();

        // S = Q K^T for this tile: 4q x 4k per thread
        float4 s[4];
        s[0] = make_float4(0.f, 0.f, 0.f, 0.f);
        s[1] = s[0]; s[2] = s[0]; s[3] = s[0];
#pragma unroll
        for (int i = 0; i < 16; ++i) {
            float4 B0 = *(const float4*)&Ks[i * 4 + 0][tx * 4];
            float4 B1 = *(const float4*)&Ks[i * 4 + 1][tx * 4];
            float4 B2 = *(const float4*)&Ks[i * 4 + 2][tx * 4];
            float4 B3 = *(const float4*)&Ks[i * 4 + 3][tx * 4];
#pragma unroll
            for (int r = 0; r < 4; ++r) {
                float4 A = *(const float4*)&Qs[qa + r][i * 4];
                FMA4(s[r], A.x, B0); FMA4(s[r], A.y, B1);
                FMA4(s[r], A.z, B2); FMA4(s[r], A.w, B3);
            }
        }
        // scale + mask invalid keys (only last tile)
        bool tail = (k0 + 64 > TKV);
#pragma unroll
        for (int r = 0; r < 4; ++r) {
            s[r].x *= SCALE_F; s[r].y *= SCALE_F;
            s[r].z *= SCALE_F; s[r].w *= SCALE_F;
        }
        if (tail) {
            int kg = k0 + tx * 4;
#pragma unroll
            for (int r = 0; r < 4; ++r) {
                if (kg + 0 >= TKV) s[r].x = -1e30f;
                if (kg + 1 >= TKV) s[r].y = -1e30f;
                if (kg + 2 >= TKV) s[r].z = -1e30f;
                if (kg + 3 >= TKV) s[r].w = -1e30f;
            }
        }

        // online softmax update per row (reduce across 16 tx lanes)
#pragma unroll
        for (int r = 0; r < 4; ++r) {
            float tmax = fmaxf(fmaxf(s[r].x, s[r].y), fmaxf(s[r].z, s[r].w));
            tmax = fmaxf(tmax, __shfl_xor(tmax, 1));
            tmax = fmaxf(tmax, __shfl_xor(tmax, 2));
            tmax = fmaxf(tmax, __shfl_xor(tmax, 4));
            tmax = fmaxf(tmax, __shfl_xor(tmax, 8));
            float mn = fmaxf(m[r], tmax);
            float alpha = __expf(m[r] - mn);
            m[r] = mn;
            float4 p;
            p.x = __expf(s[r].x - mn);
            p.y = __expf(s[r].y - mn);
            p.z = __expf(s[r].z - mn);
            p.w = __expf(s[r].w - mn);
            float tsum = p.x + p.y + p.z + p.w;
            tsum += __shfl_xor(tsum, 1);
            tsum += __shfl_xor(tsum, 2);
            tsum += __shfl_xor(tsum, 4);
            tsum += __shfl_xor(tsum, 8);
            l[r] = l[r] * alpha + tsum;
            oacc[r].x *= alpha; oacc[r].y *= alpha;
            oacc[r].z *= alpha; oacc[r].w *= alpha;
            *(float4*)&Ps[qa + r][tx * 4] = p;
        }
        __syncthreads();                 // Ps ready, K^T free

        // stage V tile: Ks[key][dim], zeros for keys past TKV
#pragma unroll
        for (int r = 0; r < 4; ++r) {
            int idx = t + 256 * r;
            int key = idx >> 4, seg = idx & 15;
            float4 v = make_float4(0.f, 0.f, 0.f, 0.f);
            int gk = k0 + key;
            if (gk < TKV) v = *(const float4*)&Vb[(size_t)gk * C_DIM + seg * 4];
            *(float4*)&Ks[key][seg * 4] = v;
        }
        __syncthreads();

        // O += P V
#pragma unroll
        for (int i = 0; i < 16; ++i) {
            float4 V0 = *(const float4*)&Ks[i * 4 + 0][tx * 4];
            float4 V1 = *(const float4*)&Ks[i * 4 + 1][tx * 4];
            float4 V2 = *(const float4*)&Ks[i * 4 + 2][tx * 4];
            float4 V3 = *(const float4*)&Ks[i * 4 + 3][tx * 4];
#pragma unroll
            for (int r = 0; r < 4; ++r) {
                float4 P = *(const float4*)&Ps[qa + r][i * 4];
                FMA4(oacc[r], P.x, V0); FMA4(oacc[r], P.y, V1);
                FMA4(oacc[r], P.z, V2); FMA4(oacc[r], P.w, V3);
            }
        }
    }

    // epilogue: normalize and store
#pragma unroll
    for (int r = 0; r < 4; ++r) {
        int gq = q0 + qa + r;
        if (gq >= TQ) continue;
        float inv = 1.f / l[r];
        float4 o = make_float4(oacc[r].x * inv, oacc[r].y * inv,
                               oacc[r].z * inv, oacc[r].w * inv);
        *(float4*)&Ob[(size_t)gq * C_DIM + tx * 4] = o;
    }
}

extern "C" void kernel_launch(void* const* d_in, const int* in_sizes, int n_in,
                              void* d_out, int out_size, void* d_ws, size_t ws_size,
                              hipStream_t stream) {
    const float* x       = (const float*)d_in[0];
    const float* conv_w  = (const float*)d_in[1];
    const float* bn_g    = (const float*)d_in[2];
    const float* bn_b    = (const float*)d_in[3];
    const float* bn_m    = (const float*)d_in[4];
    const float* bn_v    = (const float*)d_in[5];
    const float* w_q     = (const float*)d_in[6];
    const float* w_k     = (const float*)d_in[7];
    const float* w_v     = (const float*)d_in[8];
    const float* w_proj  = (const float*)d_in[9];
    const float* b_proj  = (const float*)d_in[10];
    float* out = (float*)d_out;

    const size_t NQ = (size_t)B_SZ * TQ * C_DIM;
    const size_t NKV = (size_t)B_SZ * TKV * C_DIM;

    float* ws = (float*)d_ws;
    float* q_tok = ws;
    float* k_tok = q_tok + NQ;
    float* v_tok = k_tok + NKV;
    float* Qp    = v_tok + NKV;
    float* Kp    = Qp + NQ;
    float* Vp    = Kp + NKV;
    float* attn_out = q_tok;   // q_tok dead after Q projection

    // 1) depthwise conv + BN
    {
        int total_q = B_SZ * 28 * 28 * C_DIM;
        dwconv_bn_kernel<<<(total_q + 255) / 256, 256, 0, stream>>>(
            x, conv_w + 0 * C_DIM * 9, bn_g + 0 * C_DIM, bn_b + 0 * C_DIM,
            bn_m + 0 * C_DIM, bn_v + 0 * C_DIM, q_tok, 1, 28, 28);
        int total_kv = B_SZ * 14 * 14 * C_DIM;
        dwconv_bn_kernel<<<(total_kv + 255) / 256, 256, 0, stream>>>(
            x, conv_w + 1 * C_DIM * 9, bn_g + 1 * C_DIM, bn_b + 1 * C_DIM,
            bn_m + 1 * C_DIM, bn_v + 1 * C_DIM, k_tok, 2, 14, 14);
        dwconv_bn_kernel<<<(total_kv + 255) / 256, 256, 0, stream>>>(
            x, conv_w + 2 * C_DIM * 9, bn_g + 2 * C_DIM, bn_b + 2 * C_DIM,
            bn_m + 2 * C_DIM, bn_v + 2 * C_DIM, v_tok, 2, 14, 14);
        cls_copy_kernel<<<(B_SZ * C_DIM + 255) / 256, 256, 0, stream>>>(
            x, q_tok, k_tok, v_tok);
    }

    // 2) Q/K/V projections
    {
        int Mq = B_SZ * TQ;
        int Mkv = B_SZ * TKV;
        dim3 gq(6, (Mq + 63) / 64);
        dim3 gkv(6, (Mkv + 63) / 64);
        gemm_nt_kernel<<<gq, 256, 0, stream>>>(q_tok, w_q, nullptr, Qp, Mq);
        gemm_nt_kernel<<<gkv, 256, 0, stream>>>(k_tok, w_k, nullptr, Kp, Mkv);
        gemm_nt_kernel<<<gkv, 256, 0, stream>>>(v_tok, w_v, nullptr, Vp, Mkv);
    }

    // 3) fused attention
    {
        dim3 ga((TQ + TILE_Q - 1) / TILE_Q, NH, B_SZ);
        attn_v3<<<ga, 256, 0, stream>>>(Qp, Kp, Vp, attn_out);
    }

    // 4) output projection + bias
    {
        int Mq = B_SZ * TQ;
        dim3 gp(6, (Mq + 63) / 64);
        gemm_nt_kernel<<<gp, 256, 0, stream>>>(attn_out, w_proj, b_proj, out, Mq);
    }
}

// Round 4
// 575.367 us; speedup vs baseline: 5.5836x; 1.2236x over previous
//
#include <hip/hip_runtime.h>
#include <math.h>

#define B_SZ   32
#define C_DIM  384
#define H_IN   28
#define W_IN   28
#define TQ     785   // 1 + 28*28
#define TKV    197   // 1 + 14*14
#define NH     6
#define HD     64
#define SCALE_F 0.05103103630798287f  // 384^-0.5
#define BN_EPS_F 1e-5f

#define QROWS   25120         // B_SZ*TQ
#define KVROWS  6304          // B_SZ*TKV
#define QROWS_P 25216         // padded to 128
#define KVROWS_P 6400         // padded to 128
#define WELEM   147456        // 384*384

typedef _Float16 f16;
typedef f16  f16x8 __attribute__((ext_vector_type(8)));
typedef f16  f16x4 __attribute__((ext_vector_type(4)));
typedef float f32x4 __attribute__((ext_vector_type(4)));

#define FMA4(acc, s, v) { (acc).x += (s)*(v).x; (acc).y += (s)*(v).y; (acc).z += (s)*(v).z; (acc).w += (s)*(v).w; }

__device__ __forceinline__ void split16(float v, f16& h, f16& l) {
    h = (f16)v;
    l = (f16)(v - (float)h);
}

// ---------------- weight decompose: fp32 -> f16 hi/lo ----------------
__global__ __launch_bounds__(256) void wsplit_kernel(
    const float* __restrict__ wq, const float* __restrict__ wk,
    const float* __restrict__ wv, const float* __restrict__ wp,
    f16* __restrict__ Wh, f16* __restrict__ Wl)
{
    int idx = blockIdx.x * 256 + threadIdx.x;
    if (idx >= 4 * WELEM) return;
    int which = idx / WELEM, rem = idx - which * WELEM;
    const float* s = (which == 0) ? wq : (which == 1) ? wk : (which == 2) ? wv : wp;
    f16 h, l;
    split16(s[rem], h, l);
    Wh[idx] = h; Wl[idx] = l;
}

// ---------------- depthwise 3x3 conv + BN -> f16 hi/lo tokens ----------------
__global__ __launch_bounds__(256) void dwconv_bn_kernel(
    const float* __restrict__ x,
    const float* __restrict__ cw,
    const float* __restrict__ gamma,
    const float* __restrict__ beta,
    const float* __restrict__ mean,
    const float* __restrict__ var,
    f16* __restrict__ oh, f16* __restrict__ ol,
    int stride, int HO, int WO, int TOUT)
{
    int idx = blockIdx.x * 256 + threadIdx.x;
    int total = B_SZ * HO * WO * C_DIM;
    if (idx >= total) return;
    int c = idx % C_DIM;
    int p = (idx / C_DIM) % (HO * WO);
    int b = idx / (C_DIM * HO * WO);
    int oi = p / WO, oj = p % WO;

    float acc = 0.f;
#pragma unroll
    for (int di = 0; di < 3; ++di) {
        int ii = oi * stride + di - 1;
        if (ii < 0 || ii >= H_IN) continue;
#pragma unroll
        for (int dj = 0; dj < 3; ++dj) {
            int jj = oj * stride + dj - 1;
            if (jj < 0 || jj >= W_IN) continue;
            float xv = x[((size_t)b * TQ + 1 + ii * W_IN + jj) * C_DIM + c];
            acc += cw[c * 9 + di * 3 + dj] * xv;
        }
    }
    float inv = gamma[c] * rsqrtf(var[c] + BN_EPS_F);
    float y = acc * inv + (beta[c] - mean[c] * inv);
    size_t o = ((size_t)b * TOUT + 1 + p) * C_DIM + c;
    f16 h, l;
    split16(y, h, l);
    oh[o] = h; ol[o] = l;
}

__global__ __launch_bounds__(256) void cls_copy_kernel(
    const float* __restrict__ x,
    f16* __restrict__ qh, f16* __restrict__ ql,
    f16* __restrict__ kh, f16* __restrict__ kl,
    f16* __restrict__ vh, f16* __restrict__ vl)
{
    int idx = blockIdx.x * 256 + threadIdx.x;
    if (idx >= B_SZ * C_DIM) return;
    int c = idx % C_DIM, b = idx / C_DIM;
    float v = x[(size_t)b * TQ * C_DIM + c];
    f16 h, l;
    split16(v, h, l);
    size_t oq = (size_t)b * TQ * C_DIM + c;
    size_t okv = (size_t)b * TKV * C_DIM + c;
    qh[oq] = h;  ql[oq] = l;
    kh[okv] = h; kl[okv] = l;
    vh[okv] = h; vl[okv] = l;
}

// ---------------- split-f16 MFMA GEMM ----------------
// C[m][n] = sum_k A[m][k] * W[n][k] (+bias), K = 384, N = 384.
// Split: C = Ah*Wh + Ah*Wl + Al*Wh (f16 hi/lo, fp32 acc).
// grid (3, Mtiles); block 256 = 4 waves in 2x2; each wave 64x64 (4x4 MFMA tiles).
__global__ __launch_bounds__(256) void gemm_mfma(
    const f16* __restrict__ Ah, const f16* __restrict__ Al,
    const f16* __restrict__ Wh, const f16* __restrict__ Wl,
    const float* __restrict__ bias,
    float* __restrict__ Cmat, int M)
{
    __shared__ f16 sAh[128][32];
    __shared__ f16 sAl[128][32];
    __shared__ f16 sWh[128][32];
    __shared__ f16 sWl[128][32];

    int t = threadIdx.x;
    int wv = t >> 6, lane = t & 63;
    int m0 = blockIdx.y * 128;
    int n0 = blockIdx.x * 128;
    int wr = (wv >> 1) * 64, wc = (wv & 1) * 64;
    int lrow = lane & 15, quad = lane >> 4;

    f32x4 acc[4][4];
#pragma unroll
    for (int i = 0; i < 4; ++i)
#pragma unroll
        for (int j = 0; j < 4; ++j)
            acc[i][j] = (f32x4){0.f, 0.f, 0.f, 0.f};

    for (int k0 = 0; k0 < 384; k0 += 32) {
        __syncthreads();
#pragma unroll
        for (int i = 0; i < 2; ++i) {
            int idx = t + 256 * i;
            int row = idx >> 2, seg = (idx & 3) * 8;
            *(uint4*)&sAh[row][seg] = *(const uint4*)&Ah[(size_t)(m0 + row) * 384 + k0 + seg];
            *(uint4*)&sAl[row][seg] = *(const uint4*)&Al[(size_t)(m0 + row) * 384 + k0 + seg];
            *(uint4*)&sWh[row][seg] = *(const uint4*)&Wh[(size_t)(n0 + row) * 384 + k0 + seg];
            *(uint4*)&sWl[row][seg] = *(const uint4*)&Wl[(size_t)(n0 + row) * 384 + k0 + seg];
        }
        __syncthreads();

        f16x8 bh[4], bl[4];
#pragma unroll
        for (int j = 0; j < 4; ++j) {
            bh[j] = *(const f16x8*)&sWh[wc + j * 16 + lrow][quad * 8];
            bl[j] = *(const f16x8*)&sWl[wc + j * 16 + lrow][quad * 8];
        }
#pragma unroll
        for (int i = 0; i < 4; ++i) {
            f16x8 ah = *(const f16x8*)&sAh[wr + i * 16 + lrow][quad * 8];
            f16x8 al = *(const f16x8*)&sAl[wr + i * 16 + lrow][quad * 8];
#pragma unroll
            for (int j = 0; j < 4; ++j) {
                acc[i][j] = __builtin_amdgcn_mfma_f32_16x16x32_f16(ah, bh[j], acc[i][j], 0, 0, 0);
                acc[i][j] = __builtin_amdgcn_mfma_f32_16x16x32_f16(ah, bl[j], acc[i][j], 0, 0, 0);
                acc[i][j] = __builtin_amdgcn_mfma_f32_16x16x32_f16(al, bh[j], acc[i][j], 0, 0, 0);
            }
        }
    }

    // epilogue: C/D layout col=lane&15, row=quad*4+reg
#pragma unroll
    for (int i = 0; i < 4; ++i) {
        int grow0 = m0 + wr + i * 16 + quad * 4;
#pragma unroll
        for (int j = 0; j < 4; ++j) {
            int gcol = n0 + wc + j * 16 + lrow;
            float bb = bias ? bias[gcol] : 0.f;
#pragma unroll
            for (int r = 0; r < 4; ++r) {
                int grow = grow0 + r;
                if (grow < M)
                    Cmat[(size_t)grow * 384 + gcol] = acc[i][j][r] + bb;
            }
        }
    }
}

// ---------------- flash-style fused attention (fp32), hi/lo f16 output ----------------
#define TILE_Q 64
#define KPAD   68

__global__ __launch_bounds__(256) void attn_v3(
    const float* __restrict__ Q,
    const float* __restrict__ K,
    const float* __restrict__ V,
    f16* __restrict__ Oh, f16* __restrict__ Ol)
{
    __shared__ float Qs[TILE_Q][KPAD];
    __shared__ float Ks[64][KPAD];
    __shared__ float Ps[TILE_Q][KPAD];

    int t = threadIdx.x;
    int h = blockIdx.y, b = blockIdx.z;
    int q0 = blockIdx.x * TILE_Q;
    const float* Qb = Q + (size_t)b * TQ * C_DIM + h * HD;
    const float* Kb = K + (size_t)b * TKV * C_DIM + h * HD;
    const float* Vb = V + (size_t)b * TKV * C_DIM + h * HD;

    int tx = t & 15, ty = t >> 4;
    int qa = ty * 4;

#pragma unroll
    for (int r = 0; r < 4; ++r) {
        int idx = t + 256 * r;
        int row = idx >> 4, seg = idx & 15;
        float4 v = make_float4(0.f, 0.f, 0.f, 0.f);
        int gq = q0 + row;
        if (gq < TQ) v = *(const float4*)&Qb[(size_t)gq * C_DIM + seg * 4];
        *(float4*)&Qs[row][seg * 4] = v;
    }

    float m[4] = {-1e30f, -1e30f, -1e30f, -1e30f};
    float l[4] = {0.f, 0.f, 0.f, 0.f};
    float4 oacc[4];
    oacc[0] = make_float4(0.f, 0.f, 0.f, 0.f);
    oacc[1] = oacc[0]; oacc[2] = oacc[0]; oacc[3] = oacc[0];

    for (int kt = 0; kt < 4; ++kt) {
        int k0 = kt * 64;
        __syncthreads();

#pragma unroll
        for (int r = 0; r < 4; ++r) {
            int idx = t + 256 * r;
            int key = idx >> 4, seg = idx & 15;
            float4 v = make_float4(0.f, 0.f, 0.f, 0.f);
            int gk = k0 + key;
            if (gk < TKV) v = *(const float4*)&Kb[(size_t)gk * C_DIM + seg * 4];
            Ks[seg * 4 + 0][key] = v.x;
            Ks[seg * 4 + 1][key] = v.y;
            Ks[seg * 4 + 2][key] = v.z;
            Ks[seg * 4 + 3][key] = v.w;
        }
        __syncthreads();

        float4 s[4];
        s[0] = make_float4(0.f, 0.f, 0.f, 0.f);
        s[1] = s[0]; s[2] = s[0]; s[3] = s[0];
#pragma unroll
        for (int i = 0; i < 16; ++i) {
            float4 B0 = *(const float4*)&Ks[i * 4 + 0][tx * 4];
            float4 B1 = *(const float4*)&Ks[i * 4 + 1][tx * 4];
            float4 B2 = *(const float4*)&Ks[i * 4 + 2][tx * 4];
            float4 B3 = *(const float4*)&Ks[i * 4 + 3][tx * 4];
#pragma unroll
            for (int r = 0; r < 4; ++r) {
                float4 A = *(const float4*)&Qs[qa + r][i * 4];
                FMA4(s[r], A.x, B0); FMA4(s[r], A.y, B1);
                FMA4(s[r], A.z, B2); FMA4(s[r], A.w, B3);
            }
        }
        bool tail = (k0 + 64 > TKV);
#pragma unroll
        for (int r = 0; r < 4; ++r) {
            s[r].x *= SCALE_F; s[r].y *= SCALE_F;
            s[r].z *= SCALE_F; s[r].w *= SCALE_F;
        }
        if (tail) {
            int kg = k0 + tx * 4;
#pragma unroll
            for (int r = 0; r < 4; ++r) {
                if (kg + 0 >= TKV) s[r].x = -1e30f;
                if (kg + 1 >= TKV) s[r].y = -1e30f;
                if (kg + 2 >= TKV) s[r].z = -1e30f;
                if (kg + 3 >= TKV) s[r].w = -1e30f;
            }
        }

#pragma unroll
        for (int r = 0; r < 4; ++r) {
            float tmax = fmaxf(fmaxf(s[r].x, s[r].y), fmaxf(s[r].z, s[r].w));
            tmax = fmaxf(tmax, __shfl_xor(tmax, 1));
            tmax = fmaxf(tmax, __shfl_xor(tmax, 2));
            tmax = fmaxf(tmax, __shfl_xor(tmax, 4));
            tmax = fmaxf(tmax, __shfl_xor(tmax, 8));
            float mn = fmaxf(m[r], tmax);
            float alpha = __expf(m[r] - mn);
            m[r] = mn;
            float4 p;
            p.x = __expf(s[r].x - mn);
            p.y = __expf(s[r].y - mn);
            p.z = __expf(s[r].z - mn);
            p.w = __expf(s[r].w - mn);
            float tsum = p.x + p.y + p.z + p.w;
            tsum += __shfl_xor(tsum, 1);
            tsum += __shfl_xor(tsum, 2);
            tsum += __shfl_xor(tsum, 4);
            tsum += __shfl_xor(tsum, 8);
            l[r] = l[r] * alpha + tsum;
            oacc[r].x *= alpha; oacc[r].y *= alpha;
            oacc[r].z *= alpha; oacc[r].w *= alpha;
            *(float4*)&Ps[qa + r][tx * 4] = p;
        }
        __syncthreads();

#pragma unroll
        for (int r = 0; r < 4; ++r) {
            int idx = t + 256 * r;
            int key = idx >> 4, seg = idx & 15;
            float4 v = make_float4(0.f, 0.f, 0.f, 0.f);
            int gk = k0 + key;
            if (gk < TKV) v = *(const float4*)&Vb[(size_t)gk * C_DIM + seg * 4];
            *(float4*)&Ks[key][seg * 4] = v;
        }
        __syncthreads();

#pragma unroll
        for (int i = 0; i < 16; ++i) {
            float4 V0 = *(const float4*)&Ks[i * 4 + 0][tx * 4];
            float4 V1 = *(const float4*)&Ks[i * 4 + 1][tx * 4];
            float4 V2 = *(const float4*)&Ks[i * 4 + 2][tx * 4];
            float4 V3 = *(const float4*)&Ks[i * 4 + 3][tx * 4];
#pragma unroll
            for (int r = 0; r < 4; ++r) {
                float4 P = *(const float4*)&Ps[qa + r][i * 4];
                FMA4(oacc[r], P.x, V0); FMA4(oacc[r], P.y, V1);
                FMA4(oacc[r], P.z, V2); FMA4(oacc[r], P.w, V3);
            }
        }
    }

    // epilogue: normalize, split to f16 hi/lo, store
#pragma unroll
    for (int r = 0; r < 4; ++r) {
        int gq = q0 + qa + r;
        if (gq >= TQ) continue;
        float inv = 1.f / l[r];
        float vals[4] = {oacc[r].x * inv, oacc[r].y * inv, oacc[r].z * inv, oacc[r].w * inv};
        f16x4 hv, lv;
#pragma unroll
        for (int c = 0; c < 4; ++c) {
            f16 hh, ll;
            split16(vals[c], hh, ll);
            hv[c] = hh; lv[c] = ll;
        }
        size_t off = ((size_t)b * TQ + gq) * C_DIM + h * HD + tx * 4;
        *(f16x4*)&Oh[off] = hv;
        *(f16x4*)&Ol[off] = lv;
    }
}

extern "C" void kernel_launch(void* const* d_in, const int* in_sizes, int n_in,
                              void* d_out, int out_size, void* d_ws, size_t ws_size,
                              hipStream_t stream) {
    const float* x       = (const float*)d_in[0];
    const float* conv_w  = (const float*)d_in[1];
    const float* bn_g    = (const float*)d_in[2];
    const float* bn_b    = (const float*)d_in[3];
    const float* bn_m    = (const float*)d_in[4];
    const float* bn_v    = (const float*)d_in[5];
    const float* w_q     = (const float*)d_in[6];
    const float* w_k     = (const float*)d_in[7];
    const float* w_v     = (const float*)d_in[8];
    const float* w_proj  = (const float*)d_in[9];
    const float* b_proj  = (const float*)d_in[10];
    float* out = (float*)d_out;

    // workspace layout (bytes)
    char* p = (char*)d_ws;
    const size_t QSZ  = (size_t)QROWS_P * 384 * sizeof(f16);   // 19,365,888
    const size_t KVSZ = (size_t)KVROWS_P * 384 * sizeof(f16);  //  4,915,200
    f16* qh = (f16*)p;                 p += QSZ;
    f16* ql = (f16*)p;                 p += QSZ;
    f16* vh = (f16*)p;                 p += KVSZ;
    f16* vl = (f16*)p;                 p += KVSZ;
    f16* Wh = (f16*)p;                 p += 4 * (size_t)WELEM * sizeof(f16);
    f16* Wl = (f16*)p;                 p += 4 * (size_t)WELEM * sizeof(f16);
    float* Qp = (float*)p;             p += (size_t)QROWS * 384 * sizeof(float);
    float* Kp = (float*)p;             p += (size_t)KVROWS * 384 * sizeof(float);
    f16* kh = (f16*)p;                 // kh/kl region is reused as Vp after K-proj
    f16* kl = (f16*)(p + KVSZ);
    float* Vp = (float*)p;             // alias over kh/kl (9.83 MB >= 9.69 MB needed)
    f16* oh = qh;                      // attention output reuses qh/ql (dead after Q-proj)
    f16* ol = ql;

    // 1) weight decompose
    {
        int total = 4 * WELEM;
        wsplit_kernel<<<(total + 255) / 256, 256, 0, stream>>>(w_q, w_k, w_v, w_proj, Wh, Wl);
    }

    // 2) depthwise conv + BN -> f16 hi/lo tokens
    {
        int total_q = B_SZ * 28 * 28 * C_DIM;
        dwconv_bn_kernel<<<(total_q + 255) / 256, 256, 0, stream>>>(
            x, conv_w + 0 * C_DIM * 9, bn_g + 0 * C_DIM, bn_b + 0 * C_DIM,
            bn_m + 0 * C_DIM, bn_v + 0 * C_DIM, qh, ql, 1, 28, 28, TQ);
        int total_kv = B_SZ * 14 * 14 * C_DIM;
        dwconv_bn_kernel<<<(total_kv + 255) / 256, 256, 0, stream>>>(
            x, conv_w + 1 * C_DIM * 9, bn_g + 1 * C_DIM, bn_b + 1 * C_DIM,
            bn_m + 1 * C_DIM, bn_v + 1 * C_DIM, kh, kl, 2, 14, 14, TKV);
        dwconv_bn_kernel<<<(total_kv + 255) / 256, 256, 0, stream>>>(
            x, conv_w + 2 * C_DIM * 9, bn_g + 2 * C_DIM, bn_b + 2 * C_DIM,
            bn_m + 2 * C_DIM, bn_v + 2 * C_DIM, vh, vl, 2, 14, 14, TKV);
        cls_copy_kernel<<<(B_SZ * C_DIM + 255) / 256, 256, 0, stream>>>(
            x, qh, ql, kh, kl, vh, vl);
    }

    // 3) Q/K/V projections (split-f16 MFMA). K-proj must precede V-proj (Vp aliases kh/kl).
    {
        dim3 gq(3, QROWS_P / 128);    // (3, 197)
        dim3 gkv(3, KVROWS_P / 128);  // (3, 50)
        gemm_mfma<<<gq, 256, 0, stream>>>(qh, ql, Wh + 0 * WELEM, Wl + 0 * WELEM, nullptr, Qp, QROWS);
        gemm_mfma<<<gkv, 256, 0, stream>>>(kh, kl, Wh + 1 * WELEM, Wl + 1 * WELEM, nullptr, Kp, KVROWS);
        gemm_mfma<<<gkv, 256, 0, stream>>>(vh, vl, Wh + 2 * WELEM, Wl + 2 * WELEM, nullptr, Vp, KVROWS);
    }

    // 4) fused attention (writes hi/lo f16 into oh/ol = qh/ql)
    {
        dim3 ga((TQ + TILE_Q - 1) / TILE_Q, NH, B_SZ);
        attn_v3<<<ga, 256, 0, stream>>>(Qp, Kp, Vp, oh, ol);
    }

    // 5) output projection + bias
    {
        dim3 gp(3, QROWS_P / 128);
        gemm_mfma<<<gp, 256, 0, stream>>>(oh, ol, Wh + 3 * WELEM, Wl + 3 * WELEM, b_proj, out, QROWS);
    }
}

// Round 5
// 514.445 us; speedup vs baseline: 6.2448x; 1.1184x over previous
//
#include <hip/hip_runtime.h>
#include <math.h>

#define B_SZ   32
#define C_DIM  384
#define H_IN   28
#define W_IN   28
#define TQ     785   // 1 + 28*28
#define TKV    197   // 1 + 14*14
#define NH     6
#define HD     64
#define SCALE_F 0.05103103630798287f  // 384^-0.5
#define BN_EPS_F 1e-5f

#define QROWS    25120        // B_SZ*TQ
#define KVROWS   6304         // B_SZ*TKV
#define QROWS_P  25216        // padded to 128
#define KVROWS_P 6400         // padded to 128
#define WELEM    147456       // 384*384

typedef _Float16 f16;
typedef f16  f16x8 __attribute__((ext_vector_type(8)));
typedef float f32x4 __attribute__((ext_vector_type(4)));

__device__ __forceinline__ void split16(float v, f16& h, f16& l) {
    h = (f16)v;
    l = (f16)(v - (float)h);
}

// ---------------- weight decompose: fp32 -> f16 hi/lo ----------------
__global__ __launch_bounds__(256) void wsplit_kernel(
    const float* __restrict__ wq, const float* __restrict__ wk,
    const float* __restrict__ wv, const float* __restrict__ wp,
    f16* __restrict__ Wh, f16* __restrict__ Wl)
{
    int idx = blockIdx.x * 256 + threadIdx.x;
    if (idx >= 4 * WELEM) return;
    int which = idx / WELEM, rem = idx - which * WELEM;
    const float* s = (which == 0) ? wq : (which == 1) ? wk : (which == 2) ? wv : wp;
    f16 h, l;
    split16(s[rem], h, l);
    Wh[idx] = h; Wl[idx] = l;
}

// ---------------- depthwise 3x3 conv + BN -> f16 hi/lo tokens ----------------
__global__ __launch_bounds__(256) void dwconv_bn_kernel(
    const float* __restrict__ x,
    const float* __restrict__ cw,
    const float* __restrict__ gamma,
    const float* __restrict__ beta,
    const float* __restrict__ mean,
    const float* __restrict__ var,
    f16* __restrict__ oh, f16* __restrict__ ol,
    int stride, int HO, int WO, int TOUT)
{
    int idx = blockIdx.x * 256 + threadIdx.x;
    int total = B_SZ * HO * WO * C_DIM;
    if (idx >= total) return;
    int c = idx % C_DIM;
    int p = (idx / C_DIM) % (HO * WO);
    int b = idx / (C_DIM * HO * WO);
    int oi = p / WO, oj = p % WO;

    float acc = 0.f;
#pragma unroll
    for (int di = 0; di < 3; ++di) {
        int ii = oi * stride + di - 1;
        if (ii < 0 || ii >= H_IN) continue;
#pragma unroll
        for (int dj = 0; dj < 3; ++dj) {
            int jj = oj * stride + dj - 1;
            if (jj < 0 || jj >= W_IN) continue;
            float xv = x[((size_t)b * TQ + 1 + ii * W_IN + jj) * C_DIM + c];
            acc += cw[c * 9 + di * 3 + dj] * xv;
        }
    }
    float inv = gamma[c] * rsqrtf(var[c] + BN_EPS_F);
    float y = acc * inv + (beta[c] - mean[c] * inv);
    size_t o = ((size_t)b * TOUT + 1 + p) * C_DIM + c;
    f16 h, l;
    split16(y, h, l);
    oh[o] = h; ol[o] = l;
}

__global__ __launch_bounds__(256) void cls_copy_kernel(
    const float* __restrict__ x,
    f16* __restrict__ qh, f16* __restrict__ ql,
    f16* __restrict__ kh, f16* __restrict__ kl,
    f16* __restrict__ vh, f16* __restrict__ vl)
{
    int idx = blockIdx.x * 256 + threadIdx.x;
    if (idx >= B_SZ * C_DIM) return;
    int c = idx % C_DIM, b = idx / C_DIM;
    float v = x[(size_t)b * TQ * C_DIM + c];
    f16 h, l;
    split16(v, h, l);
    size_t oq = (size_t)b * TQ * C_DIM + c;
    size_t okv = (size_t)b * TKV * C_DIM + c;
    qh[oq] = h;  ql[oq] = l;
    kh[okv] = h; kl[okv] = l;
    vh[okv] = h; vl[okv] = l;
}

// ---------------- split-f16 MFMA GEMM ----------------
// C[m][n] = sum_k A[m][k]*W[n][k] (+bias). C = Ah*Wh + Ah*Wl + Al*Wh.
// outF16: write hi/lo f16 (no bias); else f32 (+bias).
__global__ __launch_bounds__(256) void gemm_mfma(
    const f16* __restrict__ Ah, const f16* __restrict__ Al,
    const f16* __restrict__ Wh, const f16* __restrict__ Wl,
    const float* __restrict__ bias,
    float* __restrict__ Cf,
    f16* __restrict__ Coh, f16* __restrict__ Col,
    int M, int outF16)
{
    __shared__ f16 sAh[128][32];
    __shared__ f16 sAl[128][32];
    __shared__ f16 sWh[128][32];
    __shared__ f16 sWl[128][32];

    int t = threadIdx.x;
    int wv = t >> 6, lane = t & 63;
    int m0 = blockIdx.y * 128;
    int n0 = blockIdx.x * 128;
    int wr = (wv >> 1) * 64, wc = (wv & 1) * 64;
    int lrow = lane & 15, quad = lane >> 4;

    f32x4 acc[4][4];
#pragma unroll
    for (int i = 0; i < 4; ++i)
#pragma unroll
        for (int j = 0; j < 4; ++j)
            acc[i][j] = (f32x4){0.f, 0.f, 0.f, 0.f};

    for (int k0 = 0; k0 < 384; k0 += 32) {
        __syncthreads();
#pragma unroll
        for (int i = 0; i < 2; ++i) {
            int idx = t + 256 * i;
            int row = idx >> 2, seg = (idx & 3) * 8;
            *(uint4*)&sAh[row][seg] = *(const uint4*)&Ah[(size_t)(m0 + row) * 384 + k0 + seg];
            *(uint4*)&sAl[row][seg] = *(const uint4*)&Al[(size_t)(m0 + row) * 384 + k0 + seg];
            *(uint4*)&sWh[row][seg] = *(const uint4*)&Wh[(size_t)(n0 + row) * 384 + k0 + seg];
            *(uint4*)&sWl[row][seg] = *(const uint4*)&Wl[(size_t)(n0 + row) * 384 + k0 + seg];
        }
        __syncthreads();

        f16x8 bh[4], bl[4];
#pragma unroll
        for (int j = 0; j < 4; ++j) {
            bh[j] = *(const f16x8*)&sWh[wc + j * 16 + lrow][quad * 8];
            bl[j] = *(const f16x8*)&sWl[wc + j * 16 + lrow][quad * 8];
        }
#pragma unroll
        for (int i = 0; i < 4; ++i) {
            f16x8 ah = *(const f16x8*)&sAh[wr + i * 16 + lrow][quad * 8];
            f16x8 al = *(const f16x8*)&sAl[wr + i * 16 + lrow][quad * 8];
#pragma unroll
            for (int j = 0; j < 4; ++j) {
                acc[i][j] = __builtin_amdgcn_mfma_f32_16x16x32_f16(ah, bh[j], acc[i][j], 0, 0, 0);
                acc[i][j] = __builtin_amdgcn_mfma_f32_16x16x32_f16(ah, bl[j], acc[i][j], 0, 0, 0);
                acc[i][j] = __builtin_amdgcn_mfma_f32_16x16x32_f16(al, bh[j], acc[i][j], 0, 0, 0);
            }
        }
    }

    // epilogue: C/D layout col=lane&15, row=quad*4+reg
#pragma unroll
    for (int i = 0; i < 4; ++i) {
        int grow0 = m0 + wr + i * 16 + quad * 4;
#pragma unroll
        for (int j = 0; j < 4; ++j) {
            int gcol = n0 + wc + j * 16 + lrow;
            float bb = (bias && !outF16) ? bias[gcol] : 0.f;
#pragma unroll
            for (int r = 0; r < 4; ++r) {
                int grow = grow0 + r;
                if (grow >= M) continue;
                float v = acc[i][j][r] + bb;
                if (outF16) {
                    f16 h, l;
                    split16(v, h, l);
                    Coh[(size_t)grow * 384 + gcol] = h;
                    Col[(size_t)grow * 384 + gcol] = l;
                } else {
                    Cf[(size_t)grow * 384 + gcol] = v;
                }
            }
        }
    }
}

// ---------------- MFMA flash attention ----------------
// Block: 64 queries x one (b,h); 4 waves, each a 16-q strip.
// QK^T and PV via split-f16 MFMA; online softmax in C-layout registers;
// P via wave-private f32 LDS tile; V transposed on store ([d][key]).
__global__ __launch_bounds__(256) void attn_mfma(
    const f16* __restrict__ Qh, const f16* __restrict__ Ql,
    const f16* __restrict__ Kh, const f16* __restrict__ Kl,
    const f16* __restrict__ Vh, const f16* __restrict__ Vl,
    f16* __restrict__ Oh, f16* __restrict__ Ol)
{
    __shared__ f16 sQh[64][64];
    __shared__ f16 sQl[64][64];
    __shared__ f16 sKVh[64][64];   // K: [key][d]; V: [d][key] (transposed)
    __shared__ f16 sKVl[64][64];
    __shared__ float sPs[64][68];  // wave-private P strips (f32)

    int t = threadIdx.x;
    int wv = t >> 6, lane = t & 63;
    int c = lane & 15, quad = lane >> 4;
    int wq0 = wv * 16;
    int h = blockIdx.y, b = blockIdx.z;
    int q0 = blockIdx.x * 64;

    const size_t qbase = (size_t)b * TQ * C_DIM + h * HD;
    const size_t kvbase = (size_t)b * TKV * C_DIM + h * HD;

    // stage Q tile: [q][d], zero-fill rows past TQ
#pragma unroll
    for (int i = 0; i < 2; ++i) {
        int idx = t + 256 * i;            // 512 f16x8
        int row = idx >> 3, seg = (idx & 7) * 8;
        f16x8 zh = (f16x8)(f16)0.f, zl = zh;
        int gq = q0 + row;
        if (gq < TQ) {
            zh = *(const f16x8*)&Qh[qbase + (size_t)gq * C_DIM + seg];
            zl = *(const f16x8*)&Ql[qbase + (size_t)gq * C_DIM + seg];
        }
        *(f16x8*)&sQh[row][seg] = zh;
        *(f16x8*)&sQl[row][seg] = zl;
    }

    float m_r[4] = {-1e30f, -1e30f, -1e30f, -1e30f};
    float l_r[4] = {0.f, 0.f, 0.f, 0.f};
    f32x4 o[4];
#pragma unroll
    for (int j = 0; j < 4; ++j) o[j] = (f32x4){0.f, 0.f, 0.f, 0.f};

    for (int kt = 0; kt < 4; ++kt) {
        __syncthreads();                  // prev PV reads done / Q staged

        // stage K tile: [key][d]
#pragma unroll
        for (int i = 0; i < 2; ++i) {
            int idx = t + 256 * i;
            int row = idx >> 3, seg = (idx & 7) * 8;
            f16x8 zh = (f16x8)(f16)0.f, zl = zh;
            int gk = kt * 64 + row;
            if (gk < TKV) {
                zh = *(const f16x8*)&Kh[kvbase + (size_t)gk * C_DIM + seg];
                zl = *(const f16x8*)&Kl[kvbase + (size_t)gk * C_DIM + seg];
            }
            *(f16x8*)&sKVh[row][seg] = zh;
            *(f16x8*)&sKVl[row][seg] = zl;
        }
        __syncthreads();

        // S = Q K^T (split-f16)
        f32x4 s[4];
#pragma unroll
        for (int j = 0; j < 4; ++j) s[j] = (f32x4){0.f, 0.f, 0.f, 0.f};
#pragma unroll
        for (int ks = 0; ks < 2; ++ks) {
            f16x8 qh8 = *(const f16x8*)&sQh[wq0 + c][ks * 32 + quad * 8];
            f16x8 ql8 = *(const f16x8*)&sQl[wq0 + c][ks * 32 + quad * 8];
#pragma unroll
            for (int j = 0; j < 4; ++j) {
                f16x8 kh8 = *(const f16x8*)&sKVh[j * 16 + c][ks * 32 + quad * 8];
                f16x8 kl8 = *(const f16x8*)&sKVl[j * 16 + c][ks * 32 + quad * 8];
                s[j] = __builtin_amdgcn_mfma_f32_16x16x32_f16(qh8, kh8, s[j], 0, 0, 0);
                s[j] = __builtin_amdgcn_mfma_f32_16x16x32_f16(qh8, kl8, s[j], 0, 0, 0);
                s[j] = __builtin_amdgcn_mfma_f32_16x16x32_f16(ql8, kh8, s[j], 0, 0, 0);
            }
        }

        // scale + mask invalid keys
#pragma unroll
        for (int j = 0; j < 4; ++j) {
            int key = kt * 64 + j * 16 + c;
            bool bad = (key >= TKV);
#pragma unroll
            for (int r = 0; r < 4; ++r)
                s[j][r] = bad ? -1e30f : s[j][r] * SCALE_F;
        }

        // online softmax per owned row (row = wq0 + quad*4 + r)
#pragma unroll
        for (int r = 0; r < 4; ++r) {
            float mx = fmaxf(fmaxf(s[0][r], s[1][r]), fmaxf(s[2][r], s[3][r]));
            mx = fmaxf(mx, __shfl_xor(mx, 1));
            mx = fmaxf(mx, __shfl_xor(mx, 2));
            mx = fmaxf(mx, __shfl_xor(mx, 4));
            mx = fmaxf(mx, __shfl_xor(mx, 8));
            float mn = fmaxf(m_r[r], mx);
            float alpha = __expf(m_r[r] - mn);
            m_r[r] = mn;
            float psum = 0.f;
            float pj[4];
#pragma unroll
            for (int j = 0; j < 4; ++j) {
                pj[j] = __expf(s[j][r] - mn);
                psum += pj[j];
            }
            psum += __shfl_xor(psum, 1);
            psum += __shfl_xor(psum, 2);
            psum += __shfl_xor(psum, 4);
            psum += __shfl_xor(psum, 8);
            l_r[r] = l_r[r] * alpha + psum;
#pragma unroll
            for (int j = 0; j < 4; ++j) o[j][r] *= alpha;
#pragma unroll
            for (int j = 0; j < 4; ++j)
                sPs[wq0 + quad * 4 + r][j * 16 + c] = pj[j];
        }

        __syncthreads();                  // all waves done with K frags

        // stage V tile transposed: sKV[d][key]
#pragma unroll
        for (int i = 0; i < 2; ++i) {
            int idx = t + 256 * i;
            int key = idx >> 3, seg = (idx & 7) * 8;
            f16x8 zh = (f16x8)(f16)0.f, zl = zh;
            int gk = kt * 64 + key;
            if (gk < TKV) {
                zh = *(const f16x8*)&Vh[kvbase + (size_t)gk * C_DIM + seg];
                zl = *(const f16x8*)&Vl[kvbase + (size_t)gk * C_DIM + seg];
            }
#pragma unroll
            for (int ii = 0; ii < 8; ++ii) {
                sKVh[seg + ii][key] = zh[ii];
                sKVl[seg + ii][key] = zl[ii];
            }
        }
        __syncthreads();

        // O += P V (split-f16; P re-split from f32 in-register)
#pragma unroll
        for (int ks = 0; ks < 2; ++ks) {
            float4 p0 = *(const float4*)&sPs[wq0 + c][ks * 32 + quad * 8];
            float4 p1 = *(const float4*)&sPs[wq0 + c][ks * 32 + quad * 8 + 4];
            float pf[8] = {p0.x, p0.y, p0.z, p0.w, p1.x, p1.y, p1.z, p1.w};
            f16x8 ph8, pl8;
#pragma unroll
            for (int ii = 0; ii < 8; ++ii) {
                f16 hh, ll;
                split16(pf[ii], hh, ll);
                ph8[ii] = hh; pl8[ii] = ll;
            }
#pragma unroll
            for (int j = 0; j < 4; ++j) {
                f16x8 vh8 = *(const f16x8*)&sKVh[j * 16 + c][ks * 32 + quad * 8];
                f16x8 vl8 = *(const f16x8*)&sKVl[j * 16 + c][ks * 32 + quad * 8];
                o[j] = __builtin_amdgcn_mfma_f32_16x16x32_f16(ph8, vh8, o[j], 0, 0, 0);
                o[j] = __builtin_amdgcn_mfma_f32_16x16x32_f16(ph8, vl8, o[j], 0, 0, 0);
                o[j] = __builtin_amdgcn_mfma_f32_16x16x32_f16(pl8, vh8, o[j], 0, 0, 0);
            }
        }
    }

    // epilogue: normalize, split to f16 hi/lo, store
#pragma unroll
    for (int r = 0; r < 4; ++r) {
        int gq = q0 + wq0 + quad * 4 + r;
        if (gq >= TQ) continue;
        float inv = 1.f / l_r[r];
#pragma unroll
        for (int j = 0; j < 4; ++j) {
            float v = o[j][r] * inv;
            f16 hh, ll;
            split16(v, hh, ll);
            size_t off = (size_t)(b * TQ + gq) * C_DIM + h * HD + j * 16 + c;
            Oh[off] = hh;
            Ol[off] = ll;
        }
    }
}

extern "C" void kernel_launch(void* const* d_in, const int* in_sizes, int n_in,
                              void* d_out, int out_size, void* d_ws, size_t ws_size,
                              hipStream_t stream) {
    const float* x       = (const float*)d_in[0];
    const float* conv_w  = (const float*)d_in[1];
    const float* bn_g    = (const float*)d_in[2];
    const float* bn_b    = (const float*)d_in[3];
    const float* bn_m    = (const float*)d_in[4];
    const float* bn_v    = (const float*)d_in[5];
    const float* w_q     = (const float*)d_in[6];
    const float* w_k     = (const float*)d_in[7];
    const float* w_v     = (const float*)d_in[8];
    const float* w_proj  = (const float*)d_in[9];
    const float* b_proj  = (const float*)d_in[10];
    float* out = (float*)d_out;

    const size_t QSZ  = (size_t)QROWS_P * 384 * sizeof(f16);   // 19,365,888
    const size_t KVSZ = (size_t)KVROWS_P * 384 * sizeof(f16);  //  4,915,200
    const size_t WSZ  = 4 * (size_t)WELEM * sizeof(f16);       //  1,179,648

    char* p = (char*)d_ws;
    f16* qh  = (f16*)p; p += QSZ;
    f16* ql  = (f16*)p; p += QSZ;
    f16* kh  = (f16*)p; p += KVSZ;
    f16* kl  = (f16*)p; p += KVSZ;
    f16* vh  = (f16*)p; p += KVSZ;
    f16* vl  = (f16*)p; p += KVSZ;
    f16* Wh  = (f16*)p; p += WSZ;
    f16* Wl  = (f16*)p; p += WSZ;
    f16* Qph = (f16*)p; p += QSZ;
    f16* Qpl = (f16*)p; p += QSZ;
    f16* Kph = (f16*)p; p += KVSZ;
    f16* Kpl = (f16*)p; p += KVSZ;
    f16* Vph = kh;   // kh/kl dead after K-proj
    f16* Vpl = kl;
    f16* oh  = qh;   // qh/ql dead after Q-proj
    f16* ol  = ql;

    // 1) weight decompose
    wsplit_kernel<<<(4 * WELEM + 255) / 256, 256, 0, stream>>>(w_q, w_k, w_v, w_proj, Wh, Wl);

    // 2) depthwise conv + BN -> f16 hi/lo tokens
    {
        int total_q = B_SZ * 28 * 28 * C_DIM;
        dwconv_bn_kernel<<<(total_q + 255) / 256, 256, 0, stream>>>(
            x, conv_w + 0 * C_DIM * 9, bn_g + 0 * C_DIM, bn_b + 0 * C_DIM,
            bn_m + 0 * C_DIM, bn_v + 0 * C_DIM, qh, ql, 1, 28, 28, TQ);
        int total_kv = B_SZ * 14 * 14 * C_DIM;
        dwconv_bn_kernel<<<(total_kv + 255) / 256, 256, 0, stream>>>(
            x, conv_w + 1 * C_DIM * 9, bn_g + 1 * C_DIM, bn_b + 1 * C_DIM,
            bn_m + 1 * C_DIM, bn_v + 1 * C_DIM, kh, kl, 2, 14, 14, TKV);
        dwconv_bn_kernel<<<(total_kv + 255) / 256, 256, 0, stream>>>(
            x, conv_w + 2 * C_DIM * 9, bn_g + 2 * C_DIM, bn_b + 2 * C_DIM,
            bn_m + 2 * C_DIM, bn_v + 2 * C_DIM, vh, vl, 2, 14, 14, TKV);
        cls_copy_kernel<<<(B_SZ * C_DIM + 255) / 256, 256, 0, stream>>>(
            x, qh, ql, kh, kl, vh, vl);
    }

    // 3) Q/K/V projections -> hi/lo f16. K-proj BEFORE V-proj (Vph/Vpl alias kh/kl).
    {
        dim3 gq(3, QROWS_P / 128);
        dim3 gkv(3, KVROWS_P / 128);
        gemm_mfma<<<gq, 256, 0, stream>>>(qh, ql, Wh + 0 * WELEM, Wl + 0 * WELEM,
                                          nullptr, nullptr, Qph, Qpl, QROWS, 1);
        gemm_mfma<<<gkv, 256, 0, stream>>>(kh, kl, Wh + 1 * WELEM, Wl + 1 * WELEM,
                                           nullptr, nullptr, Kph, Kpl, KVROWS, 1);
        gemm_mfma<<<gkv, 256, 0, stream>>>(vh, vl, Wh + 2 * WELEM, Wl + 2 * WELEM,
                                           nullptr, nullptr, Vph, Vpl, KVROWS, 1);
    }

    // 4) MFMA flash attention -> oh/ol (aliases qh/ql)
    {
        dim3 ga((TQ + 63) / 64, NH, B_SZ);
        attn_mfma<<<ga, 256, 0, stream>>>(Qph, Qpl, Kph, Kpl, Vph, Vpl, oh, ol);
    }

    // 5) output projection + bias -> f32 out
    {
        dim3 gp(3, QROWS_P / 128);
        gemm_mfma<<<gp, 256, 0, stream>>>(oh, ol, Wh + 3 * WELEM, Wl + 3 * WELEM,
                                          b_proj, out, nullptr, nullptr, QROWS, 0);
    }
}

// Round 6
// 442.261 us; speedup vs baseline: 7.2641x; 1.1632x over previous
//
#include <hip/hip_runtime.h>
#include <math.h>

#define B_SZ   32
#define C_DIM  384
#define H_IN   28
#define W_IN   28
#define TQ     785   // 1 + 28*28
#define TKV    197   // 1 + 14*14
#define NH     6
#define HD     64
#define SCALE_F 0.05103103630798287f  // 384^-0.5
#define BN_EPS_F 1e-5f

#define QROWS    25120        // B_SZ*TQ
#define KVROWS   6304         // B_SZ*TKV
#define QROWS_P  25216        // padded to 64/128
#define KVROWS_P 6400
#define WELEM    147456       // 384*384
#define VT_LD    208          // V^T key stride (16B-aligned rows, >= 197)

typedef _Float16 f16;
typedef f16  f16x8 __attribute__((ext_vector_type(8)));
typedef float f32x4 __attribute__((ext_vector_type(4)));

__device__ __forceinline__ void split16(float v, f16& h, f16& l) {
    h = (f16)v;
    l = (f16)(v - (float)h);
}

// async global->LDS DMA, 16 B per lane. LDS side must be lane-contiguous
// (base + lane*16) -- all call sites below satisfy this (offset == idx*16).
__device__ __forceinline__ void cp16(void* lds, const void* g) {
    __builtin_amdgcn_global_load_lds(
        (const __attribute__((address_space(1))) unsigned int*)g,
        (__attribute__((address_space(3))) unsigned int*)lds, 16, 0, 0);
}

// ---------------- weight decompose: fp32 -> f16 hi/lo ----------------
__global__ __launch_bounds__(256) void wsplit_kernel(
    const float* __restrict__ wq, const float* __restrict__ wk,
    const float* __restrict__ wv, const float* __restrict__ wp,
    f16* __restrict__ Wh, f16* __restrict__ Wl)
{
    int idx = blockIdx.x * 256 + threadIdx.x;
    if (idx >= 4 * WELEM) return;
    int which = idx / WELEM, rem = idx - which * WELEM;
    const float* s = (which == 0) ? wq : (which == 1) ? wk : (which == 2) ? wv : wp;
    f16 h, l;
    split16(s[rem], h, l);
    Wh[idx] = h; Wl[idx] = l;
}

// ---------------- depthwise 3x3 conv + BN -> f16 hi/lo tokens ----------------
__global__ __launch_bounds__(256) void dwconv_bn_kernel(
    const float* __restrict__ x,
    const float* __restrict__ cw,
    const float* __restrict__ gamma,
    const float* __restrict__ beta,
    const float* __restrict__ mean,
    const float* __restrict__ var,
    f16* __restrict__ oh, f16* __restrict__ ol,
    int stride, int HO, int WO, int TOUT)
{
    int idx = blockIdx.x * 256 + threadIdx.x;
    int total = B_SZ * HO * WO * C_DIM;
    if (idx >= total) return;
    int c = idx % C_DIM;
    int p = (idx / C_DIM) % (HO * WO);
    int b = idx / (C_DIM * HO * WO);
    int oi = p / WO, oj = p % WO;

    float acc = 0.f;
#pragma unroll
    for (int di = 0; di < 3; ++di) {
        int ii = oi * stride + di - 1;
        if (ii < 0 || ii >= H_IN) continue;
#pragma unroll
        for (int dj = 0; dj < 3; ++dj) {
            int jj = oj * stride + dj - 1;
            if (jj < 0 || jj >= W_IN) continue;
            float xv = x[((size_t)b * TQ + 1 + ii * W_IN + jj) * C_DIM + c];
            acc += cw[c * 9 + di * 3 + dj] * xv;
        }
    }
    float inv = gamma[c] * rsqrtf(var[c] + BN_EPS_F);
    float y = acc * inv + (beta[c] - mean[c] * inv);
    size_t o = ((size_t)b * TOUT + 1 + p) * C_DIM + c;
    f16 h, l;
    split16(y, h, l);
    oh[o] = h; ol[o] = l;
}

__global__ __launch_bounds__(256) void cls_copy_kernel(
    const float* __restrict__ x,
    f16* __restrict__ qh, f16* __restrict__ ql,
    f16* __restrict__ kh, f16* __restrict__ kl,
    f16* __restrict__ vh, f16* __restrict__ vl)
{
    int idx = blockIdx.x * 256 + threadIdx.x;
    if (idx >= B_SZ * C_DIM) return;
    int c = idx % C_DIM, b = idx / C_DIM;
    float v = x[(size_t)b * TQ * C_DIM + c];
    f16 h, l;
    split16(v, h, l);
    size_t oq = (size_t)b * TQ * C_DIM + c;
    size_t okv = (size_t)b * TKV * C_DIM + c;
    qh[oq] = h;  ql[oq] = l;
    kh[okv] = h; kl[okv] = l;
    vh[okv] = h; vl[okv] = l;
}

// ---------------- split-f16 MFMA GEMM, 64x128 tile, global_load_lds staging ---
// C[m][n] = sum_k A[m][k]*W[n][k]. C = Ah*Wh + Ah*Wl + Al*Wh.
// mode 0: f32 + bias; mode 1: f16 hi/lo natural; mode 2: f16 hi/lo V^T store.
// grid (3, M/64); block 256 = 4 waves (2x2), wave = 32x64 = 2x4 MFMA tiles.
__global__ __launch_bounds__(256) void gemm_mfma2(
    const f16* __restrict__ Ah, const f16* __restrict__ Al,
    const f16* __restrict__ Wh, const f16* __restrict__ Wl,
    const float* __restrict__ bias,
    float* __restrict__ Cf,
    f16* __restrict__ Coh, f16* __restrict__ Col,
    int M, int mode)
{
    __shared__ f16 sAh[64][32];
    __shared__ f16 sAl[64][32];
    __shared__ f16 sWh[128][32];
    __shared__ f16 sWl[128][32];

    int t = threadIdx.x;
    int wv = t >> 6, lane = t & 63;
    int m0 = blockIdx.y * 64, n0 = blockIdx.x * 128;
    int wr = (wv >> 1) * 32, wc = (wv & 1) * 64;
    int lrow = lane & 15, quad = lane >> 4;

    int arow = t >> 2;              // 0..63
    int aseg = (t & 3) * 8;         // f16 offset, 16B units

    f32x4 acc[2][4];
#pragma unroll
    for (int i = 0; i < 2; ++i)
#pragma unroll
        for (int j = 0; j < 4; ++j)
            acc[i][j] = (f32x4){0.f, 0.f, 0.f, 0.f};

    for (int k0 = 0; k0 < 384; k0 += 32) {
        __syncthreads();
        cp16(&sAh[arow][aseg],      &Ah[(size_t)(m0 + arow) * 384 + k0 + aseg]);
        cp16(&sAl[arow][aseg],      &Al[(size_t)(m0 + arow) * 384 + k0 + aseg]);
        cp16(&sWh[arow][aseg],      &Wh[(size_t)(n0 + arow) * 384 + k0 + aseg]);
        cp16(&sWh[arow + 64][aseg], &Wh[(size_t)(n0 + arow + 64) * 384 + k0 + aseg]);
        cp16(&sWl[arow][aseg],      &Wl[(size_t)(n0 + arow) * 384 + k0 + aseg]);
        cp16(&sWl[arow + 64][aseg], &Wl[(size_t)(n0 + arow + 64) * 384 + k0 + aseg]);
        __syncthreads();

        f16x8 bh[4], bl[4];
#pragma unroll
        for (int j = 0; j < 4; ++j) {
            bh[j] = *(const f16x8*)&sWh[wc + j * 16 + lrow][quad * 8];
            bl[j] = *(const f16x8*)&sWl[wc + j * 16 + lrow][quad * 8];
        }
#pragma unroll
        for (int i = 0; i < 2; ++i) {
            f16x8 ah = *(const f16x8*)&sAh[wr + i * 16 + lrow][quad * 8];
            f16x8 al = *(const f16x8*)&sAl[wr + i * 16 + lrow][quad * 8];
#pragma unroll
            for (int j = 0; j < 4; ++j) {
                acc[i][j] = __builtin_amdgcn_mfma_f32_16x16x32_f16(ah, bh[j], acc[i][j], 0, 0, 0);
                acc[i][j] = __builtin_amdgcn_mfma_f32_16x16x32_f16(ah, bl[j], acc[i][j], 0, 0, 0);
                acc[i][j] = __builtin_amdgcn_mfma_f32_16x16x32_f16(al, bh[j], acc[i][j], 0, 0, 0);
            }
        }
    }

    // epilogue: C/D layout col=lane&15, row=quad*4+reg
#pragma unroll
    for (int i = 0; i < 2; ++i) {
        int grow0 = m0 + wr + i * 16 + quad * 4;
#pragma unroll
        for (int j = 0; j < 4; ++j) {
            int gcol = n0 + wc + j * 16 + lrow;
            float bb = (bias && mode == 0) ? bias[gcol] : 0.f;
#pragma unroll
            for (int r = 0; r < 4; ++r) {
                int grow = grow0 + r;
                if (grow >= M) continue;
                float v = acc[i][j][r] + bb;
                if (mode == 0) {
                    Cf[(size_t)grow * 384 + gcol] = v;
                } else if (mode == 1) {
                    f16 h, l;
                    split16(v, h, l);
                    Coh[(size_t)grow * 384 + gcol] = h;
                    Col[(size_t)grow * 384 + gcol] = l;
                } else {
                    // V^T: token row -> (batch, key); store [b][dim][key]
                    int bb2 = grow / TKV;
                    int key = grow - bb2 * TKV;
                    size_t off = (size_t)bb2 * 384 * VT_LD + (size_t)gcol * VT_LD + key;
                    f16 h, l;
                    split16(v, h, l);
                    Coh[off] = h;
                    Col[off] = l;
                }
            }
        }
    }
}

// ---------------- MFMA flash attention v2 ----------------
// Block: 64 queries x one (b,h); 4 waves x 16-q strips.
// LDS panels [2][64][32] (64B rows -> conflict-free b128 frag reads).
// All staging via global_load_lds; V comes pre-transposed (VT[b][dim][key]).
__global__ __launch_bounds__(256) void attn_mfma2(
    const f16* __restrict__ Qh, const f16* __restrict__ Ql,
    const f16* __restrict__ Kh, const f16* __restrict__ Kl,
    const f16* __restrict__ VTh, const f16* __restrict__ VTl,
    f16* __restrict__ Oh, f16* __restrict__ Ol)
{
    __shared__ f16 sQh[2][64][32];
    __shared__ f16 sQl[2][64][32];
    __shared__ f16 sKh[2][64][32];   // K tile, then V^T tile
    __shared__ f16 sKl[2][64][32];
    __shared__ float sPs[64][68];    // wave-private P strips (f32)

    int t = threadIdx.x;
    int wv = t >> 6, lane = t & 63;
    int c = lane & 15, quad = lane >> 4;
    int wq0 = wv * 16;
    int h = blockIdx.y, b = blockIdx.z;
    int q0 = blockIdx.x * 64;

    const size_t qbase  = (size_t)b * TQ * C_DIM + h * HD;
    const size_t kbase  = (size_t)b * TKV * C_DIM + h * HD;
    const size_t vtbase = (size_t)b * 384 * VT_LD + (size_t)h * HD * VT_LD;

    // stage Q tile: [ks][q-row][seg]; reads may spill past TQ (in-buffer, masked at store)
#pragma unroll
    for (int i = 0; i < 2; ++i) {
        int idx = t + 256 * i;
        int ks = idx >> 8, row = (idx >> 2) & 63, sg = (idx & 3) * 8;
        cp16(&sQh[ks][row][sg], &Qh[qbase + (size_t)(q0 + row) * C_DIM + ks * 32 + sg]);
        cp16(&sQl[ks][row][sg], &Ql[qbase + (size_t)(q0 + row) * C_DIM + ks * 32 + sg]);
    }

    float m_r[4] = {-1e30f, -1e30f, -1e30f, -1e30f};
    float l_r[4] = {0.f, 0.f, 0.f, 0.f};
    f32x4 o[4];
#pragma unroll
    for (int j = 0; j < 4; ++j) o[j] = (f32x4){0.f, 0.f, 0.f, 0.f};

    for (int kt = 0; kt < 4; ++kt) {
        __syncthreads();               // prev PV frag reads done

        // stage K tile [ks][key-row][seg]; spills masked via p=0
#pragma unroll
        for (int i = 0; i < 2; ++i) {
            int idx = t + 256 * i;
            int ks = idx >> 8, row = (idx >> 2) & 63, sg = (idx & 3) * 8;
            cp16(&sKh[ks][row][sg], &Kh[kbase + (size_t)(kt * 64 + row) * C_DIM + ks * 32 + sg]);
            cp16(&sKl[ks][row][sg], &Kl[kbase + (size_t)(kt * 64 + row) * C_DIM + ks * 32 + sg]);
        }
        __syncthreads();               // drains all DMA (incl. Q on first iter)

        // S = Q K^T (split-f16)
        f32x4 s[4];
#pragma unroll
        for (int j = 0; j < 4; ++j) s[j] = (f32x4){0.f, 0.f, 0.f, 0.f};
#pragma unroll
        for (int ks = 0; ks < 2; ++ks) {
            f16x8 qh8 = *(const f16x8*)&sQh[ks][wq0 + c][quad * 8];
            f16x8 ql8 = *(const f16x8*)&sQl[ks][wq0 + c][quad * 8];
#pragma unroll
            for (int j = 0; j < 4; ++j) {
                f16x8 kh8 = *(const f16x8*)&sKh[ks][j * 16 + c][quad * 8];
                f16x8 kl8 = *(const f16x8*)&sKl[ks][j * 16 + c][quad * 8];
                s[j] = __builtin_amdgcn_mfma_f32_16x16x32_f16(qh8, kh8, s[j], 0, 0, 0);
                s[j] = __builtin_amdgcn_mfma_f32_16x16x32_f16(qh8, kl8, s[j], 0, 0, 0);
                s[j] = __builtin_amdgcn_mfma_f32_16x16x32_f16(ql8, kh8, s[j], 0, 0, 0);
            }
        }

        // scale + mask invalid keys
#pragma unroll
        for (int j = 0; j < 4; ++j) {
            int key = kt * 64 + j * 16 + c;
            bool bad = (key >= TKV);
#pragma unroll
            for (int r = 0; r < 4; ++r)
                s[j][r] = bad ? -1e30f : s[j][r] * SCALE_F;
        }

        // online softmax per owned row (row = wq0 + quad*4 + r)
#pragma unroll
        for (int r = 0; r < 4; ++r) {
            float mx = fmaxf(fmaxf(s[0][r], s[1][r]), fmaxf(s[2][r], s[3][r]));
            mx = fmaxf(mx, __shfl_xor(mx, 1));
            mx = fmaxf(mx, __shfl_xor(mx, 2));
            mx = fmaxf(mx, __shfl_xor(mx, 4));
            mx = fmaxf(mx, __shfl_xor(mx, 8));
            float mn = fmaxf(m_r[r], mx);
            float alpha = __expf(m_r[r] - mn);
            m_r[r] = mn;
            float psum = 0.f;
            float pj[4];
#pragma unroll
            for (int j = 0; j < 4; ++j) {
                pj[j] = __expf(s[j][r] - mn);
                psum += pj[j];
            }
            psum += __shfl_xor(psum, 1);
            psum += __shfl_xor(psum, 2);
            psum += __shfl_xor(psum, 4);
            psum += __shfl_xor(psum, 8);
            l_r[r] = l_r[r] * alpha + psum;
#pragma unroll
            for (int j = 0; j < 4; ++j) o[j][r] *= alpha;
#pragma unroll
            for (int j = 0; j < 4; ++j)
                sPs[wq0 + quad * 4 + r][j * 16 + c] = pj[j];
        }

        __syncthreads();               // all waves done with K frags

        // stage V^T tile [ks][dim-row][key-seg]; pad keys carry junk * p=0
#pragma unroll
        for (int i = 0; i < 2; ++i) {
            int idx = t + 256 * i;
            int ks = idx >> 8, row = (idx >> 2) & 63, sg = (idx & 3) * 8;
            cp16(&sKh[ks][row][sg], &VTh[vtbase + (size_t)row * VT_LD + kt * 64 + ks * 32 + sg]);
            cp16(&sKl[ks][row][sg], &VTl[vtbase + (size_t)row * VT_LD + kt * 64 + ks * 32 + sg]);
        }
        __syncthreads();

        // O += P V (P re-split from f32)
#pragma unroll
        for (int ks = 0; ks < 2; ++ks) {
            float4 p0 = *(const float4*)&sPs[wq0 + c][ks * 32 + quad * 8];
            float4 p1 = *(const float4*)&sPs[wq0 + c][ks * 32 + quad * 8 + 4];
            float pf[8] = {p0.x, p0.y, p0.z, p0.w, p1.x, p1.y, p1.z, p1.w};
            f16x8 ph8, pl8;
#pragma unroll
            for (int ii = 0; ii < 8; ++ii) {
                f16 hh, ll;
                split16(pf[ii], hh, ll);
                ph8[ii] = hh; pl8[ii] = ll;
            }
#pragma unroll
            for (int j = 0; j < 4; ++j) {
                f16x8 vh8 = *(const f16x8*)&sKh[ks][j * 16 + c][quad * 8];
                f16x8 vl8 = *(const f16x8*)&sKl[ks][j * 16 + c][quad * 8];
                o[j] = __builtin_amdgcn_mfma_f32_16x16x32_f16(ph8, vh8, o[j], 0, 0, 0);
                o[j] = __builtin_amdgcn_mfma_f32_16x16x32_f16(ph8, vl8, o[j], 0, 0, 0);
                o[j] = __builtin_amdgcn_mfma_f32_16x16x32_f16(pl8, vh8, o[j], 0, 0, 0);
            }
        }
    }

    // epilogue: normalize, split to f16 hi/lo, store
#pragma unroll
    for (int r = 0; r < 4; ++r) {
        int gq = q0 + wq0 + quad * 4 + r;
        if (gq >= TQ) continue;
        float inv = 1.f / l_r[r];
#pragma unroll
        for (int j = 0; j < 4; ++j) {
            float v = o[j][r] * inv;
            f16 hh, ll;
            split16(v, hh, ll);
            size_t off = (size_t)(b * TQ + gq) * C_DIM + h * HD + j * 16 + c;
            Oh[off] = hh;
            Ol[off] = ll;
        }
    }
}

extern "C" void kernel_launch(void* const* d_in, const int* in_sizes, int n_in,
                              void* d_out, int out_size, void* d_ws, size_t ws_size,
                              hipStream_t stream) {
    const float* x       = (const float*)d_in[0];
    const float* conv_w  = (const float*)d_in[1];
    const float* bn_g    = (const float*)d_in[2];
    const float* bn_b    = (const float*)d_in[3];
    const float* bn_m    = (const float*)d_in[4];
    const float* bn_v    = (const float*)d_in[5];
    const float* w_q     = (const float*)d_in[6];
    const float* w_k     = (const float*)d_in[7];
    const float* w_v     = (const float*)d_in[8];
    const float* w_proj  = (const float*)d_in[9];
    const float* b_proj  = (const float*)d_in[10];
    float* out = (float*)d_out;

    const size_t QSZ  = (size_t)QROWS_P * 384 * sizeof(f16);   // 19,365,888 B
    const size_t KVSZ = (size_t)KVROWS_P * 384 * sizeof(f16);  //  4,915,200 B
    const size_t WSZ  = 4 * (size_t)WELEM * sizeof(f16);       //  1,179,648 B

    // layout: qh ql vh vl kh kl Wh Wl Qph Qpl Kph Kpl  (109.3 MB)
    // VT (hi+lo, 10.22 MB) overlays kh+kl+{wq,wk hi-slices of Wh} -- all dead
    // by the time V-proj writes it (K-proj and Q-proj run first).
    char* p = (char*)d_ws;
    f16* qh  = (f16*)p; p += QSZ;
    f16* ql  = (f16*)p; p += QSZ;
    f16* vh  = (f16*)p; p += KVSZ;
    f16* vl  = (f16*)p; p += KVSZ;
    f16* kh  = (f16*)p; p += KVSZ;
    f16* kl  = (f16*)p; p += KVSZ;
    f16* Wh  = (f16*)p; p += WSZ;
    f16* Wl  = (f16*)p; p += WSZ;
    f16* Qph = (f16*)p; p += QSZ;
    f16* Qpl = (f16*)p; p += QSZ;
    f16* Kph = (f16*)p; p += KVSZ;
    f16* Kpl = (f16*)p; p += KVSZ;

    f16* VTh = kh;                                   // 32*384*208 f16 each
    f16* VTl = VTh + (size_t)B_SZ * 384 * VT_LD;
    f16* oh  = qh;                                   // attn out over dead qh/ql
    f16* ol  = ql;

    // 1) weight decompose
    wsplit_kernel<<<(4 * WELEM + 255) / 256, 256, 0, stream>>>(w_q, w_k, w_v, w_proj, Wh, Wl);

    // 2) depthwise conv + BN -> f16 hi/lo tokens
    {
        int total_q = B_SZ * 28 * 28 * C_DIM;
        dwconv_bn_kernel<<<(total_q + 255) / 256, 256, 0, stream>>>(
            x, conv_w + 0 * C_DIM * 9, bn_g + 0 * C_DIM, bn_b + 0 * C_DIM,
            bn_m + 0 * C_DIM, bn_v + 0 * C_DIM, qh, ql, 1, 28, 28, TQ);
        int total_kv = B_SZ * 14 * 14 * C_DIM;
        dwconv_bn_kernel<<<(total_kv + 255) / 256, 256, 0, stream>>>(
            x, conv_w + 1 * C_DIM * 9, bn_g + 1 * C_DIM, bn_b + 1 * C_DIM,
            bn_m + 1 * C_DIM, bn_v + 1 * C_DIM, kh, kl, 2, 14, 14, TKV);
        dwconv_bn_kernel<<<(total_kv + 255) / 256, 256, 0, stream>>>(
            x, conv_w + 2 * C_DIM * 9, bn_g + 2 * C_DIM, bn_b + 2 * C_DIM,
            bn_m + 2 * C_DIM, bn_v + 2 * C_DIM, vh, vl, 2, 14, 14, TKV);
        cls_copy_kernel<<<(B_SZ * C_DIM + 255) / 256, 256, 0, stream>>>(
            x, qh, ql, kh, kl, vh, vl);
    }

    // 3) projections. Order matters: Q (frees wq slot), K (frees kh/kl + wk),
    //    then V which writes VT over those dead regions.
    {
        dim3 gq(3, QROWS_P / 64);     // (3, 394)
        dim3 gkv(3, KVROWS_P / 64);   // (3, 100)
        gemm_mfma2<<<gq, 256, 0, stream>>>(qh, ql, Wh + 0 * WELEM, Wl + 0 * WELEM,
                                           nullptr, nullptr, Qph, Qpl, QROWS, 1);
        gemm_mfma2<<<gkv, 256, 0, stream>>>(kh, kl, Wh + 1 * WELEM, Wl + 1 * WELEM,
                                            nullptr, nullptr, Kph, Kpl, KVROWS, 1);
        gemm_mfma2<<<gkv, 256, 0, stream>>>(vh, vl, Wh + 2 * WELEM, Wl + 2 * WELEM,
                                            nullptr, nullptr, VTh, VTl, KVROWS, 2);
    }

    // 4) MFMA flash attention -> oh/ol
    {
        dim3 ga((TQ + 63) / 64, NH, B_SZ);   // (13, 6, 32)
        attn_mfma2<<<ga, 256, 0, stream>>>(Qph, Qpl, Kph, Kpl, VTh, VTl, oh, ol);
    }

    // 5) output projection + bias -> f32 out
    {
        dim3 gp(3, QROWS_P / 64);
        gemm_mfma2<<<gp, 256, 0, stream>>>(oh, ol, Wh + 3 * WELEM, Wl + 3 * WELEM,
                                           b_proj, out, nullptr, nullptr, QROWS, 0);
    }
}

// Round 7
// 345.685 us; speedup vs baseline: 9.2935x; 1.2794x over previous
//
#include <hip/hip_runtime.h>
#include <math.h>

#define B_SZ   32
#define C_DIM  384
#define H_IN   28
#define W_IN   28
#define TQ     785   // 1 + 28*28
#define TKV    197   // 1 + 14*14
#define NH     6
#define HD     64
#define SCALE_F 0.05103103630798287f  // 384^-0.5
#define BN_EPS_F 1e-5f

#define QROWS    25120        // B_SZ*TQ
#define KVROWS   6304         // B_SZ*TKV
#define QROWS_P  25216        // padded to 64/128
#define KVROWS_P 6400
#define WELEM    147456       // 384*384
#define VT_LD    208          // V^T key stride (16B-aligned rows, >= 197)

typedef _Float16 f16;
typedef f16  f16x8 __attribute__((ext_vector_type(8)));
typedef f16  f16x4 __attribute__((ext_vector_type(4)));
typedef float f32x4 __attribute__((ext_vector_type(4)));

__device__ __forceinline__ void split16(float v, f16& h, f16& l) {
    h = (f16)v;
    l = (f16)(v - (float)h);
}

// async global->LDS DMA, 16 B per lane; LDS dest must be lane-contiguous.
__device__ __forceinline__ void cp16(void* lds, const void* g) {
    __builtin_amdgcn_global_load_lds(
        (const __attribute__((address_space(1))) unsigned int*)g,
        (__attribute__((address_space(3))) unsigned int*)lds, 16, 0, 0);
}

// ---------------- weight decompose: fp32 -> f16 hi/lo ----------------
__global__ __launch_bounds__(256) void wsplit_kernel(
    const float* __restrict__ wq, const float* __restrict__ wk,
    const float* __restrict__ wv, const float* __restrict__ wp,
    f16* __restrict__ Wh, f16* __restrict__ Wl)
{
    int idx = blockIdx.x * 256 + threadIdx.x;
    if (idx >= 4 * WELEM) return;
    int which = idx / WELEM, rem = idx - which * WELEM;
    const float* s = (which == 0) ? wq : (which == 1) ? wk : (which == 2) ? wv : wp;
    f16 h, l;
    split16(s[rem], h, l);
    Wh[idx] = h; Wl[idx] = l;
}

// ---------------- conv prep: fold BN into conv weights ----------------
// wAll[conv][t][c], t=0..8 scaled taps, t=9 bias. conv stride 3840 floats.
__global__ __launch_bounds__(256) void convprep_kernel(
    const float* __restrict__ conv_w,   // (3, 384, 1, 3, 3)
    const float* __restrict__ gamma, const float* __restrict__ beta,
    const float* __restrict__ mean, const float* __restrict__ var,
    float* __restrict__ wAll)
{
    int idx = blockIdx.x * 256 + threadIdx.x;
    if (idx >= 3 * C_DIM) return;
    int cv = idx / C_DIM, c = idx - cv * C_DIM;
    float inv = gamma[idx] * rsqrtf(var[idx] + BN_EPS_F);
#pragma unroll
    for (int t = 0; t < 9; ++t)
        wAll[cv * 3840 + t * C_DIM + c] = conv_w[(size_t)cv * C_DIM * 9 + c * 9 + t] * inv;
    wAll[cv * 3840 + 9 * C_DIM + c] = beta[idx] - mean[idx] * inv;
}

// ---------------- fused depthwise conv (Q stride1 + K/V stride2) ----------------
// Even (oi,oj): K/V conv at (oi/2,oj/2) uses the SAME 9 taps as Q at (oi,oj).
// One pass: read x once, emit Q everywhere, K+V at even pixels. float4 channels.
__global__ __launch_bounds__(256) void fused_conv_kernel(
    const float* __restrict__ x,
    const float* __restrict__ wAll,
    f16* __restrict__ qh, f16* __restrict__ ql,
    f16* __restrict__ kh, f16* __restrict__ kl,
    f16* __restrict__ vh, f16* __restrict__ vl)
{
    __shared__ float sW[3 * 3840];    // 46,080 B
    int tid = threadIdx.x;
    int oi = blockIdx.x, b = blockIdx.y;

    // stage folded weights (2880 x 16B, lane-contiguous)
#pragma unroll
    for (int i = 0; i < 12; ++i) {
        int idx = tid + 256 * i;
        if (idx < 2880) cp16(&sW[idx * 4], &wAll[idx * 4]);
    }
    __syncthreads();

    const size_t xb = (size_t)b * TQ * C_DIM + C_DIM;  // row (1 + pixel)
    bool oi_even = (oi & 1) == 0;

    for (int it = 0; it < 11; ++it) {
        int idx = tid + 256 * it;
        if (idx >= 28 * 96) break;     // uniform per wave? last iter partial -> per-thread
        int oj = idx / 96, cg = idx - oj * 96;
        int c = cg * 4;

        // load 9 taps (zero-padded at borders)
        float4 xv[9];
#pragma unroll
        for (int di = 0; di < 3; ++di) {
            int ii = oi + di - 1;
            bool rok = (ii >= 0) && (ii < H_IN);
#pragma unroll
            for (int dj = 0; dj < 3; ++dj) {
                int jj = oj + dj - 1;
                bool ok = rok && (jj >= 0) && (jj < W_IN);
                xv[di * 3 + dj] = ok ? *(const float4*)&x[xb + ((size_t)ii * W_IN + jj) * C_DIM + c]
                                     : make_float4(0.f, 0.f, 0.f, 0.f);
            }
        }

        // Q conv
        {
            float4 acc = *(const float4*)&sW[0 * 3840 + 9 * C_DIM + c];
#pragma unroll
            for (int t = 0; t < 9; ++t) {
                float4 w4 = *(const float4*)&sW[0 * 3840 + t * C_DIM + c];
                acc.x += w4.x * xv[t].x; acc.y += w4.y * xv[t].y;
                acc.z += w4.z * xv[t].z; acc.w += w4.w * xv[t].w;
            }
            f16x4 hv, lv;
            float a[4] = {acc.x, acc.y, acc.z, acc.w};
#pragma unroll
            for (int u = 0; u < 4; ++u) { f16 h, l; split16(a[u], h, l); hv[u] = h; lv[u] = l; }
            size_t off = ((size_t)b * TQ + 1 + oi * W_IN + oj) * C_DIM + c;
            *(f16x4*)&qh[off] = hv;
            *(f16x4*)&ql[off] = lv;
        }

        // K/V conv at even pixels (same taps, different weights)
        if (oi_even && ((oj & 1) == 0)) {
            int p = (oi >> 1) * 14 + (oj >> 1);
            size_t off = ((size_t)b * TKV + 1 + p) * C_DIM + c;
#pragma unroll
            for (int cv = 1; cv <= 2; ++cv) {
                float4 acc = *(const float4*)&sW[cv * 3840 + 9 * C_DIM + c];
#pragma unroll
                for (int t = 0; t < 9; ++t) {
                    float4 w4 = *(const float4*)&sW[cv * 3840 + t * C_DIM + c];
                    acc.x += w4.x * xv[t].x; acc.y += w4.y * xv[t].y;
                    acc.z += w4.z * xv[t].z; acc.w += w4.w * xv[t].w;
                }
                f16x4 hv, lv;
                float a[4] = {acc.x, acc.y, acc.z, acc.w};
#pragma unroll
                for (int u = 0; u < 4; ++u) { f16 h, l; split16(a[u], h, l); hv[u] = h; lv[u] = l; }
                if (cv == 1) { *(f16x4*)&kh[off] = hv; *(f16x4*)&kl[off] = lv; }
                else         { *(f16x4*)&vh[off] = hv; *(f16x4*)&vl[off] = lv; }
            }
        }
    }
}

__global__ __launch_bounds__(256) void cls_copy_kernel(
    const float* __restrict__ x,
    f16* __restrict__ qh, f16* __restrict__ ql,
    f16* __restrict__ kh, f16* __restrict__ kl,
    f16* __restrict__ vh, f16* __restrict__ vl)
{
    int idx = blockIdx.x * 256 + threadIdx.x;
    if (idx >= B_SZ * C_DIM) return;
    int c = idx % C_DIM, b = idx / C_DIM;
    float v = x[(size_t)b * TQ * C_DIM + c];
    f16 h, l;
    split16(v, h, l);
    size_t oq = (size_t)b * TQ * C_DIM + c;
    size_t okv = (size_t)b * TKV * C_DIM + c;
    qh[oq] = h;  ql[oq] = l;
    kh[okv] = h; kl[okv] = l;
    vh[okv] = h; vl[okv] = l;
}

// ---------------- split-f16 MFMA GEMM, 64x128 tile, global_load_lds staging ---
__global__ __launch_bounds__(256) void gemm_mfma2(
    const f16* __restrict__ Ah, const f16* __restrict__ Al,
    const f16* __restrict__ Wh, const f16* __restrict__ Wl,
    const float* __restrict__ bias,
    float* __restrict__ Cf,
    f16* __restrict__ Coh, f16* __restrict__ Col,
    int M, int mode)
{
    __shared__ f16 sAh[64][32];
    __shared__ f16 sAl[64][32];
    __shared__ f16 sWh[128][32];
    __shared__ f16 sWl[128][32];

    int t = threadIdx.x;
    int wv = t >> 6, lane = t & 63;
    int m0 = blockIdx.y * 64, n0 = blockIdx.x * 128;
    int wr = (wv >> 1) * 32, wc = (wv & 1) * 64;
    int lrow = lane & 15, quad = lane >> 4;

    int arow = t >> 2;
    int aseg = (t & 3) * 8;

    f32x4 acc[2][4];
#pragma unroll
    for (int i = 0; i < 2; ++i)
#pragma unroll
        for (int j = 0; j < 4; ++j)
            acc[i][j] = (f32x4){0.f, 0.f, 0.f, 0.f};

    for (int k0 = 0; k0 < 384; k0 += 32) {
        __syncthreads();
        cp16(&sAh[arow][aseg],      &Ah[(size_t)(m0 + arow) * 384 + k0 + aseg]);
        cp16(&sAl[arow][aseg],      &Al[(size_t)(m0 + arow) * 384 + k0 + aseg]);
        cp16(&sWh[arow][aseg],      &Wh[(size_t)(n0 + arow) * 384 + k0 + aseg]);
        cp16(&sWh[arow + 64][aseg], &Wh[(size_t)(n0 + arow + 64) * 384 + k0 + aseg]);
        cp16(&sWl[arow][aseg],      &Wl[(size_t)(n0 + arow) * 384 + k0 + aseg]);
        cp16(&sWl[arow + 64][aseg], &Wl[(size_t)(n0 + arow + 64) * 384 + k0 + aseg]);
        __syncthreads();

        f16x8 bh[4], bl[4];
#pragma unroll
        for (int j = 0; j < 4; ++j) {
            bh[j] = *(const f16x8*)&sWh[wc + j * 16 + lrow][quad * 8];
            bl[j] = *(const f16x8*)&sWl[wc + j * 16 + lrow][quad * 8];
        }
#pragma unroll
        for (int i = 0; i < 2; ++i) {
            f16x8 ah = *(const f16x8*)&sAh[wr + i * 16 + lrow][quad * 8];
            f16x8 al = *(const f16x8*)&sAl[wr + i * 16 + lrow][quad * 8];
#pragma unroll
            for (int j = 0; j < 4; ++j) {
                acc[i][j] = __builtin_amdgcn_mfma_f32_16x16x32_f16(ah, bh[j], acc[i][j], 0, 0, 0);
                acc[i][j] = __builtin_amdgcn_mfma_f32_16x16x32_f16(ah, bl[j], acc[i][j], 0, 0, 0);
                acc[i][j] = __builtin_amdgcn_mfma_f32_16x16x32_f16(al, bh[j], acc[i][j], 0, 0, 0);
            }
        }
    }

#pragma unroll
    for (int i = 0; i < 2; ++i) {
        int grow0 = m0 + wr + i * 16 + quad * 4;
#pragma unroll
        for (int j = 0; j < 4; ++j) {
            int gcol = n0 + wc + j * 16 + lrow;
            float bb = (bias && mode == 0) ? bias[gcol] : 0.f;
#pragma unroll
            for (int r = 0; r < 4; ++r) {
                int grow = grow0 + r;
                if (grow >= M) continue;
                float v = acc[i][j][r] + bb;
                if (mode == 0) {
                    Cf[(size_t)grow * 384 + gcol] = v;
                } else if (mode == 1) {
                    f16 h, l;
                    split16(v, h, l);
                    Coh[(size_t)grow * 384 + gcol] = h;
                    Col[(size_t)grow * 384 + gcol] = l;
                } else {
                    int bb2 = grow / TKV;
                    int key = grow - bb2 * TKV;
                    size_t off = (size_t)bb2 * 384 * VT_LD + (size_t)gcol * VT_LD + key;
                    f16 h, l;
                    split16(v, h, l);
                    Coh[off] = h;
                    Col[off] = l;
                }
            }
        }
    }
}

// ---------------- MFMA flash attention v2 ----------------
__global__ __launch_bounds__(256) void attn_mfma2(
    const f16* __restrict__ Qh, const f16* __restrict__ Ql,
    const f16* __restrict__ Kh, const f16* __restrict__ Kl,
    const f16* __restrict__ VTh, const f16* __restrict__ VTl,
    f16* __restrict__ Oh, f16* __restrict__ Ol)
{
    __shared__ f16 sQh[2][64][32];
    __shared__ f16 sQl[2][64][32];
    __shared__ f16 sKh[2][64][32];
    __shared__ f16 sKl[2][64][32];
    __shared__ float sPs[64][68];

    int t = threadIdx.x;
    int wv = t >> 6, lane = t & 63;
    int c = lane & 15, quad = lane >> 4;
    int wq0 = wv * 16;
    int h = blockIdx.y, b = blockIdx.z;
    int q0 = blockIdx.x * 64;

    const size_t qbase  = (size_t)b * TQ * C_DIM + h * HD;
    const size_t kbase  = (size_t)b * TKV * C_DIM + h * HD;
    const size_t vtbase = (size_t)b * 384 * VT_LD + (size_t)h * HD * VT_LD;

#pragma unroll
    for (int i = 0; i < 2; ++i) {
        int idx = t + 256 * i;
        int ks = idx >> 8, row = (idx >> 2) & 63, sg = (idx & 3) * 8;
        cp16(&sQh[ks][row][sg], &Qh[qbase + (size_t)(q0 + row) * C_DIM + ks * 32 + sg]);
        cp16(&sQl[ks][row][sg], &Ql[qbase + (size_t)(q0 + row) * C_DIM + ks * 32 + sg]);
    }

    float m_r[4] = {-1e30f, -1e30f, -1e30f, -1e30f};
    float l_r[4] = {0.f, 0.f, 0.f, 0.f};
    f32x4 o[4];
#pragma unroll
    for (int j = 0; j < 4; ++j) o[j] = (f32x4){0.f, 0.f, 0.f, 0.f};

    for (int kt = 0; kt < 4; ++kt) {
        __syncthreads();

#pragma unroll
        for (int i = 0; i < 2; ++i) {
            int idx = t + 256 * i;
            int ks = idx >> 8, row = (idx >> 2) & 63, sg = (idx & 3) * 8;
            cp16(&sKh[ks][row][sg], &Kh[kbase + (size_t)(kt * 64 + row) * C_DIM + ks * 32 + sg]);
            cp16(&sKl[ks][row][sg], &Kl[kbase + (size_t)(kt * 64 + row) * C_DIM + ks * 32 + sg]);
        }
        __syncthreads();

        f32x4 s[4];
#pragma unroll
        for (int j = 0; j < 4; ++j) s[j] = (f32x4){0.f, 0.f, 0.f, 0.f};
#pragma unroll
        for (int ks = 0; ks < 2; ++ks) {
            f16x8 qh8 = *(const f16x8*)&sQh[ks][wq0 + c][quad * 8];
            f16x8 ql8 = *(const f16x8*)&sQl[ks][wq0 + c][quad * 8];
#pragma unroll
            for (int j = 0; j < 4; ++j) {
                f16x8 kh8 = *(const f16x8*)&sKh[ks][j * 16 + c][quad * 8];
                f16x8 kl8 = *(const f16x8*)&sKl[ks][j * 16 + c][quad * 8];
                s[j] = __builtin_amdgcn_mfma_f32_16x16x32_f16(qh8, kh8, s[j], 0, 0, 0);
                s[j] = __builtin_amdgcn_mfma_f32_16x16x32_f16(qh8, kl8, s[j], 0, 0, 0);
                s[j] = __builtin_amdgcn_mfma_f32_16x16x32_f16(ql8, kh8, s[j], 0, 0, 0);
            }
        }

#pragma unroll
        for (int j = 0; j < 4; ++j) {
            int key = kt * 64 + j * 16 + c;
            bool bad = (key >= TKV);
#pragma unroll
            for (int r = 0; r < 4; ++r)
                s[j][r] = bad ? -1e30f : s[j][r] * SCALE_F;
        }

#pragma unroll
        for (int r = 0; r < 4; ++r) {
            float mx = fmaxf(fmaxf(s[0][r], s[1][r]), fmaxf(s[2][r], s[3][r]));
            mx = fmaxf(mx, __shfl_xor(mx, 1));
            mx = fmaxf(mx, __shfl_xor(mx, 2));
            mx = fmaxf(mx, __shfl_xor(mx, 4));
            mx = fmaxf(mx, __shfl_xor(mx, 8));
            float mn = fmaxf(m_r[r], mx);
            float alpha = __expf(m_r[r] - mn);
            m_r[r] = mn;
            float psum = 0.f;
            float pj[4];
#pragma unroll
            for (int j = 0; j < 4; ++j) {
                pj[j] = __expf(s[j][r] - mn);
                psum += pj[j];
            }
            psum += __shfl_xor(psum, 1);
            psum += __shfl_xor(psum, 2);
            psum += __shfl_xor(psum, 4);
            psum += __shfl_xor(psum, 8);
            l_r[r] = l_r[r] * alpha + psum;
#pragma unroll
            for (int j = 0; j < 4; ++j) o[j][r] *= alpha;
#pragma unroll
            for (int j = 0; j < 4; ++j)
                sPs[wq0 + quad * 4 + r][j * 16 + c] = pj[j];
        }

        __syncthreads();

#pragma unroll
        for (int i = 0; i < 2; ++i) {
            int idx = t + 256 * i;
            int ks = idx >> 8, row = (idx >> 2) & 63, sg = (idx & 3) * 8;
            cp16(&sKh[ks][row][sg], &VTh[vtbase + (size_t)row * VT_LD + kt * 64 + ks * 32 + sg]);
            cp16(&sKl[ks][row][sg], &VTl[vtbase + (size_t)row * VT_LD + kt * 64 + ks * 32 + sg]);
        }
        __syncthreads();

#pragma unroll
        for (int ks = 0; ks < 2; ++ks) {
            float4 p0 = *(const float4*)&sPs[wq0 + c][ks * 32 + quad * 8];
            float4 p1 = *(const float4*)&sPs[wq0 + c][ks * 32 + quad * 8 + 4];
            float pf[8] = {p0.x, p0.y, p0.z, p0.w, p1.x, p1.y, p1.z, p1.w};
            f16x8 ph8, pl8;
#pragma unroll
            for (int ii = 0; ii < 8; ++ii) {
                f16 hh, ll;
                split16(pf[ii], hh, ll);
                ph8[ii] = hh; pl8[ii] = ll;
            }
#pragma unroll
            for (int j = 0; j < 4; ++j) {
                f16x8 vh8 = *(const f16x8*)&sKh[ks][j * 16 + c][quad * 8];
                f16x8 vl8 = *(const f16x8*)&sKl[ks][j * 16 + c][quad * 8];
                o[j] = __builtin_amdgcn_mfma_f32_16x16x32_f16(ph8, vh8, o[j], 0, 0, 0);
                o[j] = __builtin_amdgcn_mfma_f32_16x16x32_f16(ph8, vl8, o[j], 0, 0, 0);
                o[j] = __builtin_amdgcn_mfma_f32_16x16x32_f16(pl8, vh8, o[j], 0, 0, 0);
            }
        }
    }

#pragma unroll
    for (int r = 0; r < 4; ++r) {
        int gq = q0 + wq0 + quad * 4 + r;
        if (gq >= TQ) continue;
        float inv = 1.f / l_r[r];
#pragma unroll
        for (int j = 0; j < 4; ++j) {
            float v = o[j][r] * inv;
            f16 hh, ll;
            split16(v, hh, ll);
            size_t off = (size_t)(b * TQ + gq) * C_DIM + h * HD + j * 16 + c;
            Oh[off] = hh;
            Ol[off] = ll;
        }
    }
}

extern "C" void kernel_launch(void* const* d_in, const int* in_sizes, int n_in,
                              void* d_out, int out_size, void* d_ws, size_t ws_size,
                              hipStream_t stream) {
    const float* x       = (const float*)d_in[0];
    const float* conv_w  = (const float*)d_in[1];
    const float* bn_g    = (const float*)d_in[2];
    const float* bn_b    = (const float*)d_in[3];
    const float* bn_m    = (const float*)d_in[4];
    const float* bn_v    = (const float*)d_in[5];
    const float* w_q     = (const float*)d_in[6];
    const float* w_k     = (const float*)d_in[7];
    const float* w_v     = (const float*)d_in[8];
    const float* w_proj  = (const float*)d_in[9];
    const float* b_proj  = (const float*)d_in[10];
    float* out = (float*)d_out;

    const size_t QSZ  = (size_t)QROWS_P * 384 * sizeof(f16);
    const size_t KVSZ = (size_t)KVROWS_P * 384 * sizeof(f16);
    const size_t WSZ  = 4 * (size_t)WELEM * sizeof(f16);

    char* p = (char*)d_ws;
    f16* qh  = (f16*)p; p += QSZ;
    f16* ql  = (f16*)p; p += QSZ;
    f16* vh  = (f16*)p; p += KVSZ;
    f16* vl  = (f16*)p; p += KVSZ;
    f16* kh  = (f16*)p; p += KVSZ;
    f16* kl  = (f16*)p; p += KVSZ;
    f16* Wh  = (f16*)p; p += WSZ;
    f16* Wl  = (f16*)p; p += WSZ;
    f16* Qph = (f16*)p; p += QSZ;
    f16* Qpl = (f16*)p; p += QSZ;
    f16* Kph = (f16*)p; p += KVSZ;
    f16* Kpl = (f16*)p; p += KVSZ;
    float* wAll = (float*)p; p += 3 * 3840 * sizeof(float);

    f16* VTh = kh;
    f16* VTl = VTh + (size_t)B_SZ * 384 * VT_LD;
    f16* oh  = qh;
    f16* ol  = ql;

    // 1) weight decompose + conv/BN fold
    wsplit_kernel<<<(4 * WELEM + 255) / 256, 256, 0, stream>>>(w_q, w_k, w_v, w_proj, Wh, Wl);
    convprep_kernel<<<(3 * C_DIM + 255) / 256, 256, 0, stream>>>(
        conv_w, bn_g, bn_b, bn_m, bn_v, wAll);

    // 2) fused conv (Q + K + V in one pass) + cls token
    {
        dim3 gc(H_IN, B_SZ);   // (28, 32)
        fused_conv_kernel<<<gc, 256, 0, stream>>>(x, wAll, qh, ql, kh, kl, vh, vl);
        cls_copy_kernel<<<(B_SZ * C_DIM + 255) / 256, 256, 0, stream>>>(
            x, qh, ql, kh, kl, vh, vl);
    }

    // 3) projections. Q first (frees nothing but order-safe), K before V
    //    (V-proj writes VT over dead kh/kl + wq/wk hi-slices).
    {
        dim3 gq(3, QROWS_P / 64);
        dim3 gkv(3, KVROWS_P / 64);
        gemm_mfma2<<<gq, 256, 0, stream>>>(qh, ql, Wh + 0 * WELEM, Wl + 0 * WELEM,
                                           nullptr, nullptr, Qph, Qpl, QROWS, 1);
        gemm_mfma2<<<gkv, 256, 0, stream>>>(kh, kl, Wh + 1 * WELEM, Wl + 1 * WELEM,
                                            nullptr, nullptr, Kph, Kpl, KVROWS, 1);
        gemm_mfma2<<<gkv, 256, 0, stream>>>(vh, vl, Wh + 2 * WELEM, Wl + 2 * WELEM,
                                            nullptr, nullptr, VTh, VTl, KVROWS, 2);
    }

    // 4) MFMA flash attention -> oh/ol
    {
        dim3 ga((TQ + 63) / 64, NH, B_SZ);
        attn_mfma2<<<ga, 256, 0, stream>>>(Qph, Qpl, Kph, Kpl, VTh, VTl, oh, ol);
    }

    // 5) output projection + bias -> f32 out
    {
        dim3 gp(3, QROWS_P / 64);
        gemm_mfma2<<<gp, 256, 0, stream>>>(oh, ol, Wh + 3 * WELEM, Wl + 3 * WELEM,
                                           b_proj, out, nullptr, nullptr, QROWS, 0);
    }
}

// Round 8
// 298.415 us; speedup vs baseline: 10.7656x; 1.1584x over previous
//
#include <hip/hip_runtime.h>
#include <math.h>

#define B_SZ   32
#define C_DIM  384
#define H_IN   28
#define W_IN   28
#define TQ     785   // 1 + 28*28
#define TKV    197   // 1 + 14*14
#define NH     6
#define HD     64
#define SCALE_F 0.05103103630798287f       // 384^-0.5
#define SCALE_L2E (0.05103103630798287f * 1.4426950408889634f)  // fold log2(e): use exp2 in softmax
#define BN_EPS_F 1e-5f

#define QROWS    25120        // B_SZ*TQ
#define KVROWS   6304         // B_SZ*TKV
#define QROWS_P  25216        // padded to 64/128
#define KVROWS_P 6400
#define WELEM    147456       // 384*384
#define VT_LD    208          // V^T key stride (16B-aligned rows, >= 197)

typedef _Float16 f16;
typedef f16  f16x8 __attribute__((ext_vector_type(8)));
typedef f16  f16x4 __attribute__((ext_vector_type(4)));
typedef float f32x4 __attribute__((ext_vector_type(4)));

__device__ __forceinline__ void split16(float v, f16& h, f16& l) {
    h = (f16)v;
    l = (f16)(v - (float)h);
}

// async global->LDS DMA, 16 B per lane; LDS dest must be lane-contiguous.
__device__ __forceinline__ void cp16(void* lds, const void* g) {
    __builtin_amdgcn_global_load_lds(
        (const __attribute__((address_space(1))) unsigned int*)g,
        (__attribute__((address_space(3))) unsigned int*)lds, 16, 0, 0);
}

// ---------------- prep: weight decompose (+scale fold into w_q) + conv/BN fold --
__global__ __launch_bounds__(256) void prep_kernel(
    const float* __restrict__ wq, const float* __restrict__ wk,
    const float* __restrict__ wv, const float* __restrict__ wp,
    const float* __restrict__ conv_w,
    const float* __restrict__ gamma, const float* __restrict__ beta,
    const float* __restrict__ mean, const float* __restrict__ var,
    f16* __restrict__ Wh, f16* __restrict__ Wl,
    float* __restrict__ wAll)
{
    int idx = blockIdx.x * 256 + threadIdx.x;
    if (idx < 4 * WELEM) {
        int which = idx / WELEM, rem = idx - which * WELEM;
        const float* s = (which == 0) ? wq : (which == 1) ? wk : (which == 2) ? wv : wp;
        float v = s[rem];
        if (which == 0) v *= SCALE_L2E;   // QK^T logits come out in log2 domain
        f16 h, l;
        split16(v, h, l);
        Wh[idx] = h; Wl[idx] = l;
    } else if (idx < 4 * WELEM + 3 * C_DIM) {
        int k = idx - 4 * WELEM;
        int cv = k / C_DIM, c = k - cv * C_DIM;
        float inv = gamma[k] * rsqrtf(var[k] + BN_EPS_F);
#pragma unroll
        for (int t = 0; t < 9; ++t)
            wAll[cv * 3840 + t * C_DIM + c] = conv_w[(size_t)cv * C_DIM * 9 + c * 9 + t] * inv;
        wAll[cv * 3840 + 9 * C_DIM + c] = beta[k] - mean[k] * inv;
    }
}

// ---------------- fused depthwise conv (Q stride1 + K/V stride2) + cls row -----
__global__ __launch_bounds__(256) void fused_conv_kernel(
    const float* __restrict__ x,
    const float* __restrict__ wAll,
    f16* __restrict__ qh, f16* __restrict__ ql,
    f16* __restrict__ kh, f16* __restrict__ kl,
    f16* __restrict__ vh, f16* __restrict__ vl)
{
    __shared__ float sW[3 * 3840];
    int tid = threadIdx.x;
    int oi = blockIdx.x, b = blockIdx.y;

    if (oi == H_IN) {                 // cls-token path
        if (tid < 96) {
            int c = tid * 4;
            float4 v = *(const float4*)&x[(size_t)b * TQ * C_DIM + c];
            float a[4] = {v.x, v.y, v.z, v.w};
            f16x4 hv, lv;
#pragma unroll
            for (int u = 0; u < 4; ++u) { f16 h, l; split16(a[u], h, l); hv[u] = h; lv[u] = l; }
            size_t oq = (size_t)b * TQ * C_DIM + c;
            size_t okv = (size_t)b * TKV * C_DIM + c;
            *(f16x4*)&qh[oq] = hv;  *(f16x4*)&ql[oq] = lv;
            *(f16x4*)&kh[okv] = hv; *(f16x4*)&kl[okv] = lv;
            *(f16x4*)&vh[okv] = hv; *(f16x4*)&vl[okv] = lv;
        }
        return;
    }

#pragma unroll
    for (int i = 0; i < 12; ++i) {
        int idx = tid + 256 * i;
        if (idx < 2880) cp16(&sW[idx * 4], &wAll[idx * 4]);
    }
    __syncthreads();

    const size_t xb = (size_t)b * TQ * C_DIM + C_DIM;
    bool oi_even = (oi & 1) == 0;

    for (int it = 0; it < 11; ++it) {
        int idx = tid + 256 * it;
        if (idx >= 28 * 96) break;
        int oj = idx / 96, cg = idx - oj * 96;
        int c = cg * 4;

        float4 xv[9];
#pragma unroll
        for (int di = 0; di < 3; ++di) {
            int ii = oi + di - 1;
            bool rok = (ii >= 0) && (ii < H_IN);
#pragma unroll
            for (int dj = 0; dj < 3; ++dj) {
                int jj = oj + dj - 1;
                bool ok = rok && (jj >= 0) && (jj < W_IN);
                xv[di * 3 + dj] = ok ? *(const float4*)&x[xb + ((size_t)ii * W_IN + jj) * C_DIM + c]
                                     : make_float4(0.f, 0.f, 0.f, 0.f);
            }
        }

        {
            float4 acc = *(const float4*)&sW[0 * 3840 + 9 * C_DIM + c];
#pragma unroll
            for (int t = 0; t < 9; ++t) {
                float4 w4 = *(const float4*)&sW[0 * 3840 + t * C_DIM + c];
                acc.x += w4.x * xv[t].x; acc.y += w4.y * xv[t].y;
                acc.z += w4.z * xv[t].z; acc.w += w4.w * xv[t].w;
            }
            f16x4 hv, lv;
            float a[4] = {acc.x, acc.y, acc.z, acc.w};
#pragma unroll
            for (int u = 0; u < 4; ++u) { f16 h, l; split16(a[u], h, l); hv[u] = h; lv[u] = l; }
            size_t off = ((size_t)b * TQ + 1 + oi * W_IN + oj) * C_DIM + c;
            *(f16x4*)&qh[off] = hv;
            *(f16x4*)&ql[off] = lv;
        }

        if (oi_even && ((oj & 1) == 0)) {
            int p = (oi >> 1) * 14 + (oj >> 1);
            size_t off = ((size_t)b * TKV + 1 + p) * C_DIM + c;
#pragma unroll
            for (int cv = 1; cv <= 2; ++cv) {
                float4 acc = *(const float4*)&sW[cv * 3840 + 9 * C_DIM + c];
#pragma unroll
                for (int t = 0; t < 9; ++t) {
                    float4 w4 = *(const float4*)&sW[cv * 3840 + t * C_DIM + c];
                    acc.x += w4.x * xv[t].x; acc.y += w4.y * xv[t].y;
                    acc.z += w4.z * xv[t].z; acc.w += w4.w * xv[t].w;
                }
                f16x4 hv, lv;
                float a[4] = {acc.x, acc.y, acc.z, acc.w};
#pragma unroll
                for (int u = 0; u < 4; ++u) { f16 h, l; split16(a[u], h, l); hv[u] = h; lv[u] = l; }
                if (cv == 1) { *(f16x4*)&kh[off] = hv; *(f16x4*)&kl[off] = lv; }
                else         { *(f16x4*)&vh[off] = hv; *(f16x4*)&vl[off] = lv; }
            }
        }
    }
}

// ---------------- split-f16 MFMA GEMM body (64x128 tile, DMA staging) ----------
__device__ __forceinline__ void gemm_body(
    const f16* __restrict__ Ah, const f16* __restrict__ Al,
    const f16* __restrict__ Wh, const f16* __restrict__ Wl,
    const float* __restrict__ bias,
    float* __restrict__ Cf, f16* __restrict__ Coh, f16* __restrict__ Col,
    int M, int mode, int m0, int n0)
{
    __shared__ f16 sAh[64][32];
    __shared__ f16 sAl[64][32];
    __shared__ f16 sWh[128][32];
    __shared__ f16 sWl[128][32];

    int t = threadIdx.x;
    int wv = t >> 6, lane = t & 63;
    int wr = (wv >> 1) * 32, wc = (wv & 1) * 64;
    int lrow = lane & 15, quad = lane >> 4;
    int arow = t >> 2;
    int aseg = (t & 3) * 8;

    f32x4 acc[2][4];
#pragma unroll
    for (int i = 0; i < 2; ++i)
#pragma unroll
        for (int j = 0; j < 4; ++j)
            acc[i][j] = (f32x4){0.f, 0.f, 0.f, 0.f};

    for (int k0 = 0; k0 < 384; k0 += 32) {
        __syncthreads();
        cp16(&sAh[arow][aseg],      &Ah[(size_t)(m0 + arow) * 384 + k0 + aseg]);
        cp16(&sAl[arow][aseg],      &Al[(size_t)(m0 + arow) * 384 + k0 + aseg]);
        cp16(&sWh[arow][aseg],      &Wh[(size_t)(n0 + arow) * 384 + k0 + aseg]);
        cp16(&sWh[arow + 64][aseg], &Wh[(size_t)(n0 + arow + 64) * 384 + k0 + aseg]);
        cp16(&sWl[arow][aseg],      &Wl[(size_t)(n0 + arow) * 384 + k0 + aseg]);
        cp16(&sWl[arow + 64][aseg], &Wl[(size_t)(n0 + arow + 64) * 384 + k0 + aseg]);
        __syncthreads();

        f16x8 bh[4], bl[4];
#pragma unroll
        for (int j = 0; j < 4; ++j) {
            bh[j] = *(const f16x8*)&sWh[wc + j * 16 + lrow][quad * 8];
            bl[j] = *(const f16x8*)&sWl[wc + j * 16 + lrow][quad * 8];
        }
#pragma unroll
        for (int i = 0; i < 2; ++i) {
            f16x8 ah = *(const f16x8*)&sAh[wr + i * 16 + lrow][quad * 8];
            f16x8 al = *(const f16x8*)&sAl[wr + i * 16 + lrow][quad * 8];
#pragma unroll
            for (int j = 0; j < 4; ++j) {
                acc[i][j] = __builtin_amdgcn_mfma_f32_16x16x32_f16(ah, bh[j], acc[i][j], 0, 0, 0);
                acc[i][j] = __builtin_amdgcn_mfma_f32_16x16x32_f16(ah, bl[j], acc[i][j], 0, 0, 0);
                acc[i][j] = __builtin_amdgcn_mfma_f32_16x16x32_f16(al, bh[j], acc[i][j], 0, 0, 0);
            }
        }
    }

#pragma unroll
    for (int i = 0; i < 2; ++i) {
        int grow0 = m0 + wr + i * 16 + quad * 4;
#pragma unroll
        for (int j = 0; j < 4; ++j) {
            int gcol = n0 + wc + j * 16 + lrow;
            float bb = (bias && mode == 0) ? bias[gcol] : 0.f;
#pragma unroll
            for (int r = 0; r < 4; ++r) {
                int grow = grow0 + r;
                if (grow >= M) continue;
                float v = acc[i][j][r] + bb;
                if (mode == 0) {
                    Cf[(size_t)grow * 384 + gcol] = v;
                } else if (mode == 1) {
                    f16 h, l;
                    split16(v, h, l);
                    Coh[(size_t)grow * 384 + gcol] = h;
                    Col[(size_t)grow * 384 + gcol] = l;
                } else {
                    int bb2 = grow / TKV;
                    int key = grow - bb2 * TKV;
                    size_t off = (size_t)bb2 * 384 * VT_LD + (size_t)gcol * VT_LD + key;
                    f16 h, l;
                    split16(v, h, l);
                    Coh[off] = h;
                    Col[off] = l;
                }
            }
        }
    }
}

// merged Q/K/V projections: z picks which problem; early-exit unused y-tiles
__global__ __launch_bounds__(256) void qkv_proj_kernel(
    const f16* __restrict__ qh, const f16* __restrict__ ql,
    const f16* __restrict__ kh, const f16* __restrict__ kl,
    const f16* __restrict__ vh, const f16* __restrict__ vl,
    const f16* __restrict__ Wh, const f16* __restrict__ Wl,
    f16* __restrict__ Qph, f16* __restrict__ Qpl,
    f16* __restrict__ Kph, f16* __restrict__ Kpl,
    f16* __restrict__ VTh, f16* __restrict__ VTl)
{
    int z = blockIdx.z;
    int ytiles = (z == 0) ? (QROWS_P / 64) : (KVROWS_P / 64);
    if ((int)blockIdx.y >= ytiles) return;
    int m0 = blockIdx.y * 64, n0 = blockIdx.x * 128;
    if (z == 0)
        gemm_body(qh, ql, Wh, Wl, nullptr, nullptr, Qph, Qpl, QROWS, 1, m0, n0);
    else if (z == 1)
        gemm_body(kh, kl, Wh + WELEM, Wl + WELEM, nullptr, nullptr, Kph, Kpl, KVROWS, 1, m0, n0);
    else
        gemm_body(vh, vl, Wh + 2 * WELEM, Wl + 2 * WELEM, nullptr, nullptr, VTh, VTl, KVROWS, 2, m0, n0);
}

__global__ __launch_bounds__(256) void out_proj_kernel(
    const f16* __restrict__ Ah, const f16* __restrict__ Al,
    const f16* __restrict__ Wh, const f16* __restrict__ Wl,
    const float* __restrict__ bias, float* __restrict__ Cf)
{
    gemm_body(Ah, Al, Wh, Wl, bias, Cf, nullptr, nullptr, QROWS, 0,
              blockIdx.y * 64, blockIdx.x * 128);
}

// ---------------- MFMA attention v3: non-flash single-pass softmax ----------
// Phase 1: S for all 4 K-tiles in registers (logits already in log2 domain
// via SCALE*log2e folded into w_q). Phase 2: one max/exp2/sum pass.
// Phase 3: PV per V^T tile via wave-private sPs round-trip.
__global__ __launch_bounds__(256) void attn_mfma3(
    const f16* __restrict__ Qh, const f16* __restrict__ Ql,
    const f16* __restrict__ Kh, const f16* __restrict__ Kl,
    const f16* __restrict__ VTh, const f16* __restrict__ VTl,
    f16* __restrict__ Oh, f16* __restrict__ Ol)
{
    __shared__ f16 sQh[2][64][32];
    __shared__ f16 sQl[2][64][32];
    __shared__ f16 sKh[2][64][32];
    __shared__ f16 sKl[2][64][32];
    __shared__ float sPs[64][68];

    int t = threadIdx.x;
    int wv = t >> 6, lane = t & 63;
    int c = lane & 15, quad = lane >> 4;
    int wq0 = wv * 16;
    int h = blockIdx.y, b = blockIdx.z;
    int q0 = blockIdx.x * 64;

    const size_t qbase  = (size_t)b * TQ * C_DIM + h * HD;
    const size_t kbase  = (size_t)b * TKV * C_DIM + h * HD;
    const size_t vtbase = (size_t)b * 384 * VT_LD + (size_t)h * HD * VT_LD;

    // stage Q tile
#pragma unroll
    for (int i = 0; i < 2; ++i) {
        int idx = t + 256 * i;
        int ks = idx >> 8, row = (idx >> 2) & 63, sg = (idx & 3) * 8;
        cp16(&sQh[ks][row][sg], &Qh[qbase + (size_t)(q0 + row) * C_DIM + ks * 32 + sg]);
        cp16(&sQl[ks][row][sg], &Ql[qbase + (size_t)(q0 + row) * C_DIM + ks * 32 + sg]);
    }

    f32x4 s[4][4];
#pragma unroll
    for (int kt = 0; kt < 4; ++kt)
#pragma unroll
        for (int j = 0; j < 4; ++j)
            s[kt][j] = (f32x4){0.f, 0.f, 0.f, 0.f};

    // ---- phase 1: all S tiles ----
#pragma unroll
    for (int kt = 0; kt < 4; ++kt) {
        __syncthreads();               // prev K-panel frag reads done
#pragma unroll
        for (int i = 0; i < 2; ++i) {
            int idx = t + 256 * i;
            int ks = idx >> 8, row = (idx >> 2) & 63, sg = (idx & 3) * 8;
            cp16(&sKh[ks][row][sg], &Kh[kbase + (size_t)(kt * 64 + row) * C_DIM + ks * 32 + sg]);
            cp16(&sKl[ks][row][sg], &Kl[kbase + (size_t)(kt * 64 + row) * C_DIM + ks * 32 + sg]);
        }
        __syncthreads();               // drains DMA (incl. Q on first iter)

#pragma unroll
        for (int ks = 0; ks < 2; ++ks) {
            f16x8 qh8 = *(const f16x8*)&sQh[ks][wq0 + c][quad * 8];
            f16x8 ql8 = *(const f16x8*)&sQl[ks][wq0 + c][quad * 8];
#pragma unroll
            for (int j = 0; j < 4; ++j) {
                f16x8 kh8 = *(const f16x8*)&sKh[ks][j * 16 + c][quad * 8];
                f16x8 kl8 = *(const f16x8*)&sKl[ks][j * 16 + c][quad * 8];
                s[kt][j] = __builtin_amdgcn_mfma_f32_16x16x32_f16(qh8, kh8, s[kt][j], 0, 0, 0);
                s[kt][j] = __builtin_amdgcn_mfma_f32_16x16x32_f16(qh8, kl8, s[kt][j], 0, 0, 0);
                s[kt][j] = __builtin_amdgcn_mfma_f32_16x16x32_f16(ql8, kh8, s[kt][j], 0, 0, 0);
            }
        }
    }

    // ---- phase 2: mask tail + single softmax pass (log2 domain) ----
#pragma unroll
    for (int r = 0; r < 4; ++r) {
        s[3][0][r] = (c < 5) ? s[3][0][r] : -1e30f;  // keys 192..196 valid
        s[3][1][r] = -1e30f;
        s[3][2][r] = -1e30f;
        s[3][3][r] = -1e30f;
    }

    float inv_r[4];
#pragma unroll
    for (int r = 0; r < 4; ++r) {
        float mx = -1e30f;
#pragma unroll
        for (int kt = 0; kt < 4; ++kt)
#pragma unroll
            for (int j = 0; j < 4; ++j)
                mx = fmaxf(mx, s[kt][j][r]);
        mx = fmaxf(mx, __shfl_xor(mx, 1));
        mx = fmaxf(mx, __shfl_xor(mx, 2));
        mx = fmaxf(mx, __shfl_xor(mx, 4));
        mx = fmaxf(mx, __shfl_xor(mx, 8));
        float sum = 0.f;
#pragma unroll
        for (int kt = 0; kt < 4; ++kt)
#pragma unroll
            for (int j = 0; j < 4; ++j) {
                float pv = exp2f(s[kt][j][r] - mx);
                s[kt][j][r] = pv;
                sum += pv;
            }
        sum += __shfl_xor(sum, 1);
        sum += __shfl_xor(sum, 2);
        sum += __shfl_xor(sum, 4);
        sum += __shfl_xor(sum, 8);
        inv_r[r] = 1.f / sum;
    }

    // ---- phase 3: O = P V ----
    f32x4 o[4];
#pragma unroll
    for (int j = 0; j < 4; ++j) o[j] = (f32x4){0.f, 0.f, 0.f, 0.f};

#pragma unroll
    for (int vt = 0; vt < 4; ++vt) {
        // write this wave's P strip (wave-private rows)
#pragma unroll
        for (int r = 0; r < 4; ++r)
#pragma unroll
            for (int j = 0; j < 4; ++j)
                sPs[wq0 + quad * 4 + r][j * 16 + c] = s[vt][j][r];

        __syncthreads();               // prev panel reads (S-phase or PV) done
#pragma unroll
        for (int i = 0; i < 2; ++i) {
            int idx = t + 256 * i;
            int ks = idx >> 8, row = (idx >> 2) & 63, sg = (idx & 3) * 8;
            cp16(&sKh[ks][row][sg], &VTh[vtbase + (size_t)row * VT_LD + vt * 64 + ks * 32 + sg]);
            cp16(&sKl[ks][row][sg], &VTl[vtbase + (size_t)row * VT_LD + vt * 64 + ks * 32 + sg]);
        }
        __syncthreads();

#pragma unroll
        for (int ks = 0; ks < 2; ++ks) {
            float4 p0 = *(const float4*)&sPs[wq0 + c][ks * 32 + quad * 8];
            float4 p1 = *(const float4*)&sPs[wq0 + c][ks * 32 + quad * 8 + 4];
            float pf[8] = {p0.x, p0.y, p0.z, p0.w, p1.x, p1.y, p1.z, p1.w};
            f16x8 ph8, pl8;
#pragma unroll
            for (int ii = 0; ii < 8; ++ii) {
                f16 hh, ll;
                split16(pf[ii], hh, ll);
                ph8[ii] = hh; pl8[ii] = ll;
            }
#pragma unroll
            for (int j = 0; j < 4; ++j) {
                f16x8 vh8 = *(const f16x8*)&sKh[ks][j * 16 + c][quad * 8];
                f16x8 vl8 = *(const f16x8*)&sKl[ks][j * 16 + c][quad * 8];
                o[j] = __builtin_amdgcn_mfma_f32_16x16x32_f16(ph8, vh8, o[j], 0, 0, 0);
                o[j] = __builtin_amdgcn_mfma_f32_16x16x32_f16(ph8, vl8, o[j], 0, 0, 0);
                o[j] = __builtin_amdgcn_mfma_f32_16x16x32_f16(pl8, vh8, o[j], 0, 0, 0);
            }
        }
    }

    // epilogue
#pragma unroll
    for (int r = 0; r < 4; ++r) {
        int gq = q0 + wq0 + quad * 4 + r;
        if (gq >= TQ) continue;
        float inv = inv_r[r];
#pragma unroll
        for (int j = 0; j < 4; ++j) {
            float v = o[j][r] * inv;
            f16 hh, ll;
            split16(v, hh, ll);
            size_t off = (size_t)(b * TQ + gq) * C_DIM + h * HD + j * 16 + c;
            Oh[off] = hh;
            Ol[off] = ll;
        }
    }
}

extern "C" void kernel_launch(void* const* d_in, const int* in_sizes, int n_in,
                              void* d_out, int out_size, void* d_ws, size_t ws_size,
                              hipStream_t stream) {
    const float* x       = (const float*)d_in[0];
    const float* conv_w  = (const float*)d_in[1];
    const float* bn_g    = (const float*)d_in[2];
    const float* bn_b    = (const float*)d_in[3];
    const float* bn_m    = (const float*)d_in[4];
    const float* bn_v    = (const float*)d_in[5];
    const float* w_q     = (const float*)d_in[6];
    const float* w_k     = (const float*)d_in[7];
    const float* w_v     = (const float*)d_in[8];
    const float* w_proj  = (const float*)d_in[9];
    const float* b_proj  = (const float*)d_in[10];
    float* out = (float*)d_out;

    const size_t QSZ  = (size_t)QROWS_P * 384 * sizeof(f16);
    const size_t KVSZ = (size_t)KVROWS_P * 384 * sizeof(f16);
    const size_t WSZ  = 4 * (size_t)WELEM * sizeof(f16);

    char* p = (char*)d_ws;
    f16* qh  = (f16*)p; p += QSZ;
    f16* ql  = (f16*)p; p += QSZ;
    f16* vh  = (f16*)p; p += KVSZ;
    f16* vl  = (f16*)p; p += KVSZ;
    f16* kh  = (f16*)p; p += KVSZ;
    f16* kl  = (f16*)p; p += KVSZ;
    f16* Wh  = (f16*)p; p += WSZ;
    f16* Wl  = (f16*)p; p += WSZ;
    f16* Qph = (f16*)p; p += QSZ;
    f16* Qpl = (f16*)p; p += QSZ;
    f16* Kph = (f16*)p; p += KVSZ;
    f16* Kpl = (f16*)p; p += KVSZ;
    float* wAll = (float*)p; p += 3 * 3840 * sizeof(float);

    f16* VTh = kh;                     // VT overlays dead kh/kl + wq/wk hi-slices
    f16* VTl = VTh + (size_t)B_SZ * 384 * VT_LD;
    f16* oh  = qh;                     // attn out over dead qh/ql
    f16* ol  = ql;

    // 1) prep: weight split (+SCALE*log2e fold into w_q) + conv/BN fold
    {
        int total = 4 * WELEM + 3 * C_DIM;
        prep_kernel<<<(total + 255) / 256, 256, 0, stream>>>(
            w_q, w_k, w_v, w_proj, conv_w, bn_g, bn_b, bn_m, bn_v, Wh, Wl, wAll);
    }

    // 2) fused conv (Q + K + V + cls in one launch)
    {
        dim3 gc(H_IN + 1, B_SZ);       // (29, 32); x==28 is the cls path
        fused_conv_kernel<<<gc, 256, 0, stream>>>(x, wAll, qh, ql, kh, kl, vh, vl);
    }

    // 3) merged Q/K/V projections (z = which). V-proj writes VT over dead kh/kl.
    {
        dim3 g(3, QROWS_P / 64, 3);    // (3, 394, 3)
        qkv_proj_kernel<<<g, 256, 0, stream>>>(qh, ql, kh, kl, vh, vl, Wh, Wl,
                                               Qph, Qpl, Kph, Kpl, VTh, VTl);
    }

    // 4) MFMA attention v3 -> oh/ol
    {
        dim3 ga((TQ + 63) / 64, NH, B_SZ);
        attn_mfma3<<<ga, 256, 0, stream>>>(Qph, Qpl, Kph, Kpl, VTh, VTl, oh, ol);
    }

    // 5) output projection + bias -> f32 out
    {
        dim3 gp(3, QROWS_P / 64);
        out_proj_kernel<<<gp, 256, 0, stream>>>(oh, ol, Wh + 3 * WELEM, Wl + 3 * WELEM,
                                                b_proj, out);
    }
}